// Round 3
// baseline (531.663 us; speedup 1.0000x reference)
//
#include <hip/hip_runtime.h>
#include <hip/hip_bf16.h>
#include <stdint.h>

// ---------------------------------------------------------------------------
// SmallTransformerBlock on MI355X (gfx950)  — Round 11
//   B=4, T=2048, D=1024, FF=4096, full-D attention, scale = sqrt(128)
// R10 -> R11: fix gemm8's LDS/MFMA serialization (measured: MfmaUtil 38%,
// dur 76.8us on FFN1 — phase = lgkm(0)-drain THEN MFMA, lockstep barriers).
//   * ds_reads hoisted one phase ahead: each phase's post-barrier region
//     issues the NEXT phase's operand reads, then a COUNTED lgkmcnt wait
//     (4/8/0/none per phase) covering only reads issued >=2 phases earlier.
//     LDS pipe drains next-phase operands during this phase's MFMA cluster.
//   * tile-residency vmcnt moved end-of-P4/P8 -> end-of-P3/P7 as vmcnt(2)
//     so the closing barrier PUBLISHES all waves' staging before the
//     hoisted buffer-switch reads (per-wave vmcnt doesn't cover other
//     waves' global_load_lds).
//   * WAR ledger re-derived: every stage into region X issues >=1 closing
//     barrier after X's last read is completion-guaranteed by a counted wait.
// ---------------------------------------------------------------------------

typedef __bf16 bf16x8 __attribute__((ext_vector_type(8)));
typedef float f32x4 __attribute__((ext_vector_type(4)));

__device__ __forceinline__ unsigned short f2b(float f) {
    __hip_bfloat16 h = __float2bfloat16(f);
    unsigned short u;
    __builtin_memcpy(&u, &h, 2);
    return u;
}

__device__ __forceinline__ float b2f(unsigned short u) {
    __hip_bfloat16 h;
    __builtin_memcpy(&h, &u, 2);
    return __bfloat162float(h);
}

__device__ __forceinline__ void async_copy16(const unsigned short* g, unsigned short* l) {
    __builtin_amdgcn_global_load_lds((__attribute__((address_space(1))) void*)(g),
                                     (__attribute__((address_space(3))) void*)(l),
                                     16, 0, 0);
}

// ---------------------------------------------------------------------------
// gemm8: C[M,N] = A[M,K] @ Bt[N,K]^T, 256x256 tile, BK=64, 8-phase schedule
// with one-phase-ahead register pipelining.
// MODE 0: +bias   MODE 1: exp(acc*scale-16)   MODE 4: +bias, relu
// grid = (N/256, M/256, batch), block = 512. Requires K % 128 == 0.
//
// Steady state (tile t even in buf0, t+1 in buf1):
//   reads R(p) issued in phase p's post-barrier region, consumed phase p+1:
//     R(P8')=buf0 ks0 (12)  R(P1)=buf0.B ks1 (4)  R(P2)=buf0.A ks1 (8)
//     R(P3)=none  R(P4)=buf1 ks0 (12)  R(P5)=buf1.B ks1 (4)
//     R(P6)=buf1.A ks1 (8)  R(P7)=none
//   waits before MFMA: P1 lgkm(4), P2 lgkm(8), P3 lgkm(0), P4 -,
//                      P5 lgkm(4), P6 lgkm(8), P7 lgkm(0), P8 -
//   (counted waits retire oldest-first -> safe even if b128 reads split)
//   stages (pre-barrier region, 2 gload_lds each):
//     P1:(t+1).Bh1  P2:(t+1).Ah1  P3:(t+2).Bh0  P4:(t+2).Ah0
//     P5:(t+2).Bh1  P6:(t+2).Ah1  P7:(t+3).Bh0  P8:(t+3).Ah0
//   vmcnt(2) at END of P3/P7 (before the closing barrier): retires through
//   S(P2)/S(P6) -> next tile fully staged, published to all waves by the
//   closing barrier, before R(P4)/R(P8) read the switched buffer.
// ---------------------------------------------------------------------------
template <int MODE>
__launch_bounds__(512, 2)
__global__ void gemm8(const unsigned short* __restrict__ A, int lda,
                      const unsigned short* __restrict__ Bt, int ldb,
                      unsigned short* __restrict__ Cv, int ldc,
                      const float* __restrict__ bias,
                      int M, int N, int K,
                      long sA, long sB, long sC, float scale) {
    constexpr bool HAS_BIAS = (MODE == 0 || MODE == 4);
    constexpr bool RELU     = (MODE == 4);
    constexpr bool EXPW     = (MODE == 1);

    __shared__ unsigned short lds8[65536];  // 128 KiB: [buf][A 16384 | B 16384]

    // XCD-aware swizzle (nwg % 8 == 0 for all our grids)
    const int nx = (int)gridDim.x, ny = (int)gridDim.y;
    int bx, by;
    if ((ny & 7) == 0) {
        const int n     = (int)blockIdx.y * nx + (int)blockIdx.x;
        const int xcd   = n & 7;
        const int slot  = n >> 3;
        const int bandh = ny >> 3;
        by = xcd * bandh + (slot % bandh);
        bx = slot / bandh;
    } else {
        bx = (int)blockIdx.x;
        by = (int)blockIdx.y;
    }

    const int z = blockIdx.z;
    const unsigned short* Ab = A + (long)z * sA + (long)by * 256 * lda;
    const unsigned short* Bb = Bt + (long)z * sB + (long)bx * 256 * ldb;

    const int tid  = threadIdx.x;
    const int lane = tid & 63;
    const int wid  = tid >> 6;
    const int wm   = wid >> 2;   // 0..1 -> 128 rows
    const int wn   = wid & 3;    // 0..3 -> 64 cols
    const int rr   = lane & 15;
    const int kq   = lane >> 4;
    const int s7   = rr & 7;
    const int cK0  = (kq ^ s7) * 8;         // swizzled chunk offset, ks=0
    const int cK1  = ((4 | kq) ^ s7) * 8;   // ks=1

    // staging: 1024 chunks per half-tile, 2 calls x 512 threads.
    // LDS slot (r, c) holds global chunk c ^ (r&7)  [XOR swizzle; read side
    // applies the same XOR -> conflict-free (2 lanes/16B-slot per 16-lane
    // LDS quarter-wave group = free), 0 conflicts measured]
    long offA[2], offB[2];
    int dstp[2];
#pragma unroll
    for (int j = 0; j < 2; ++j) {
        const int s = j * 512 + tid;
        const int r = s >> 3;
        const int c = ((s & 7) ^ (r & 7)) * 8;
        offA[j] = (long)r * lda + c;
        offB[j] = (long)r * ldb + c;
        dstp[j] = (j * 512 + wid * 64) * 8;   // elems; HW adds lane*16B
    }

#define STAGE_A8(buf, half, kt) do {                                          \
    const unsigned short* _s = Ab + (long)(half) * 128 * lda + ((kt) << 6);   \
    unsigned short* _d = lds8 + (buf) * 32768 + (half) * 8192;                \
    async_copy16(_s + offA[0], _d + dstp[0]);                                 \
    async_copy16(_s + offA[1], _d + dstp[1]);                                 \
} while (0)
#define STAGE_B8(buf, half, kt) do {                                          \
    const unsigned short* _s = Bb + (long)(half) * 128 * ldb + ((kt) << 6);   \
    unsigned short* _d = lds8 + (buf) * 32768 + 16384 + (half) * 8192;        \
    async_copy16(_s + offB[0], _d + dstp[0]);                                 \
    async_copy16(_s + offB[1], _d + dstp[1]);                                 \
} while (0)

    const int nt = K >> 6;   // K-tiles (even; K % 128 == 0)

    f32x4 acc[8][4] = {};
    bf16x8 a0[8], a1[8], b0[4], b1[4];

    const int aRow = wm * 128 + rr;
    const int bRow = wn * 64 + rr;
    const unsigned short* lA0 = lds8;
    const unsigned short* lB0 = lds8 + 16384;
    const unsigned short* lA1 = lds8 + 32768;
    const unsigned short* lB1 = lds8 + 32768 + 16384;

    // prologue: tile0 -> buf0 (all 4 halves), tile1 -> buf1 (Bh0 Ah0)
    STAGE_B8(0, 0, 0); STAGE_A8(0, 0, 0); STAGE_B8(0, 1, 0); STAGE_A8(0, 1, 0);
    STAGE_B8(1, 0, 1); STAGE_A8(1, 0, 1);
    asm volatile("s_waitcnt vmcnt(4)" ::: "memory");   // tile0 resident (own wave)
    __builtin_amdgcn_s_barrier();                      // publish tile0 cross-wave
    // R0: buf0 ks0 operands for P1/P2 (12 reads, in flight into the loop)
#pragma unroll
    for (int m = 0; m < 8; ++m) a0[m] = *(const bf16x8*)(lA0 + (aRow + m * 16) * 64 + cK0);
#pragma unroll
    for (int n = 0; n < 4; ++n) b0[n] = *(const bf16x8*)(lB0 + (bRow + n * 16) * 64 + cK0);

    for (int it = 0; it < (nt >> 1); ++it) {
        const int t = it * 2;
        int t2 = t + 2; if (t2 >= nt) t2 -= nt;   // wrapped stages at the
        int t3 = t + 3; if (t3 >= nt) t3 -= nt;   // tail are harmless (WAR-safe)

        // ---- P1: stage (t+1).Bh1; read-ahead b1 (buf0 ks1); MFMA a0*b0[0:1]
        STAGE_B8(1, 1, t + 1);
        __builtin_amdgcn_s_barrier();
#pragma unroll
        for (int n = 0; n < 4; ++n) b1[n] = *(const bf16x8*)(lB0 + (bRow + n * 16) * 64 + cK1);
        asm volatile("s_waitcnt lgkmcnt(4)" ::: "memory");   // a0,b0 ready; b1 in flight
        __builtin_amdgcn_sched_barrier(0);
        __builtin_amdgcn_s_setprio(1);
#pragma unroll
        for (int m = 0; m < 8; ++m) {
            acc[m][0] = __builtin_amdgcn_mfma_f32_16x16x32_bf16(a0[m], b0[0], acc[m][0], 0, 0, 0);
            acc[m][1] = __builtin_amdgcn_mfma_f32_16x16x32_bf16(a0[m], b0[1], acc[m][1], 0, 0, 0);
        }
        __builtin_amdgcn_s_setprio(0);
        __builtin_amdgcn_s_barrier();

        // ---- P2: stage (t+1).Ah1; read-ahead a1 (buf0 ks1); MFMA a0*b0[2:3]
        STAGE_A8(1, 1, t + 1);
        __builtin_amdgcn_s_barrier();
#pragma unroll
        for (int m = 0; m < 8; ++m) a1[m] = *(const bf16x8*)(lA0 + (aRow + m * 16) * 64 + cK1);
        asm volatile("s_waitcnt lgkmcnt(8)" ::: "memory");   // b1 ready (WAR for S(P3)); a1 in flight
        __builtin_amdgcn_sched_barrier(0);
        __builtin_amdgcn_s_setprio(1);
#pragma unroll
        for (int m = 0; m < 8; ++m) {
            acc[m][2] = __builtin_amdgcn_mfma_f32_16x16x32_bf16(a0[m], b0[2], acc[m][2], 0, 0, 0);
            acc[m][3] = __builtin_amdgcn_mfma_f32_16x16x32_bf16(a0[m], b0[3], acc[m][3], 0, 0, 0);
        }
        __builtin_amdgcn_s_setprio(0);
        __builtin_amdgcn_s_barrier();

        // ---- P3: stage (t+2).Bh0 -> buf0 (B reads done by cb(P2));
        //          MFMA a1*b1[0:1]; vmcnt(2): tile t+1 staged (publish at cb)
        STAGE_B8(0, 0, t2);
        __builtin_amdgcn_s_barrier();
        asm volatile("s_waitcnt lgkmcnt(0)" ::: "memory");   // a1 (and b1) ready
        __builtin_amdgcn_sched_barrier(0);
        __builtin_amdgcn_s_setprio(1);
#pragma unroll
        for (int m = 0; m < 8; ++m) {
            acc[m][0] = __builtin_amdgcn_mfma_f32_16x16x32_bf16(a1[m], b1[0], acc[m][0], 0, 0, 0);
            acc[m][1] = __builtin_amdgcn_mfma_f32_16x16x32_bf16(a1[m], b1[1], acc[m][1], 0, 0, 0);
        }
        __builtin_amdgcn_s_setprio(0);
        asm volatile("s_waitcnt vmcnt(2)" ::: "memory");     // through S(P2): t+1 resident
        __builtin_amdgcn_s_barrier();

        // ---- P4: stage (t+2).Ah0 -> buf0 (A reads done by cb(P3));
        //          read-ahead a0,b0 <- buf1 ks0 (published cb(P3)); MFMA a1*b1[2:3]
        STAGE_A8(0, 0, t2);
        __builtin_amdgcn_s_barrier();
#pragma unroll
        for (int m = 0; m < 8; ++m) a0[m] = *(const bf16x8*)(lA1 + (aRow + m * 16) * 64 + cK0);
#pragma unroll
        for (int n = 0; n < 4; ++n) b0[n] = *(const bf16x8*)(lB1 + (bRow + n * 16) * 64 + cK0);
        __builtin_amdgcn_sched_barrier(0);                   // reads issue before MFMA
        __builtin_amdgcn_s_setprio(1);
#pragma unroll
        for (int m = 0; m < 8; ++m) {
            acc[m][2] = __builtin_amdgcn_mfma_f32_16x16x32_bf16(a1[m], b1[2], acc[m][2], 0, 0, 0);
            acc[m][3] = __builtin_amdgcn_mfma_f32_16x16x32_bf16(a1[m], b1[3], acc[m][3], 0, 0, 0);
        }
        __builtin_amdgcn_s_setprio(0);
        __builtin_amdgcn_s_barrier();

        // ---- P5: stage (t+2).Bh1 -> buf0; read-ahead b1 (buf1 ks1); MFMA a0*b0[0:1]
        STAGE_B8(0, 1, t2);
        __builtin_amdgcn_s_barrier();
#pragma unroll
        for (int n = 0; n < 4; ++n) b1[n] = *(const bf16x8*)(lB1 + (bRow + n * 16) * 64 + cK1);
        asm volatile("s_waitcnt lgkmcnt(4)" ::: "memory");   // a0,b0 (buf1) ready
        __builtin_amdgcn_sched_barrier(0);
        __builtin_amdgcn_s_setprio(1);
#pragma unroll
        for (int m = 0; m < 8; ++m) {
            acc[m][0] = __builtin_amdgcn_mfma_f32_16x16x32_bf16(a0[m], b0[0], acc[m][0], 0, 0, 0);
            acc[m][1] = __builtin_amdgcn_mfma_f32_16x16x32_bf16(a0[m], b0[1], acc[m][1], 0, 0, 0);
        }
        __builtin_amdgcn_s_setprio(0);
        __builtin_amdgcn_s_barrier();

        // ---- P6: stage (t+2).Ah1 -> buf0; read-ahead a1 (buf1 ks1); MFMA a0*b0[2:3]
        STAGE_A8(0, 1, t2);
        __builtin_amdgcn_s_barrier();
#pragma unroll
        for (int m = 0; m < 8; ++m) a1[m] = *(const bf16x8*)(lA1 + (aRow + m * 16) * 64 + cK1);
        asm volatile("s_waitcnt lgkmcnt(8)" ::: "memory");   // b1 ready (WAR for S(P7))
        __builtin_amdgcn_sched_barrier(0);
        __builtin_amdgcn_s_setprio(1);
#pragma unroll
        for (int m = 0; m < 8; ++m) {
            acc[m][2] = __builtin_amdgcn_mfma_f32_16x16x32_bf16(a0[m], b0[2], acc[m][2], 0, 0, 0);
            acc[m][3] = __builtin_amdgcn_mfma_f32_16x16x32_bf16(a0[m], b0[3], acc[m][3], 0, 0, 0);
        }
        __builtin_amdgcn_s_setprio(0);
        __builtin_amdgcn_s_barrier();

        // ---- P7: stage (t+3).Bh0 -> buf1; MFMA a1*b1[0:1]; vmcnt(2): t+2 staged
        STAGE_B8(1, 0, t3);
        __builtin_amdgcn_s_barrier();
        asm volatile("s_waitcnt lgkmcnt(0)" ::: "memory");   // a1 ready
        __builtin_amdgcn_sched_barrier(0);
        __builtin_amdgcn_s_setprio(1);
#pragma unroll
        for (int m = 0; m < 8; ++m) {
            acc[m][0] = __builtin_amdgcn_mfma_f32_16x16x32_bf16(a1[m], b1[0], acc[m][0], 0, 0, 0);
            acc[m][1] = __builtin_amdgcn_mfma_f32_16x16x32_bf16(a1[m], b1[1], acc[m][1], 0, 0, 0);
        }
        __builtin_amdgcn_s_setprio(0);
        asm volatile("s_waitcnt vmcnt(2)" ::: "memory");     // through S(P6): t+2 resident
        __builtin_amdgcn_s_barrier();

        // ---- P8: stage (t+3).Ah0 -> buf1; read-ahead a0,b0 <- buf0 (t+2) ks0;
        //          MFMA a1*b1[2:3]
        STAGE_A8(1, 0, t3);
        __builtin_amdgcn_s_barrier();
#pragma unroll
        for (int m = 0; m < 8; ++m) a0[m] = *(const bf16x8*)(lA0 + (aRow + m * 16) * 64 + cK0);
#pragma unroll
        for (int n = 0; n < 4; ++n) b0[n] = *(const bf16x8*)(lB0 + (bRow + n * 16) * 64 + cK0);
        __builtin_amdgcn_sched_barrier(0);
        __builtin_amdgcn_s_setprio(1);
#pragma unroll
        for (int m = 0; m < 8; ++m) {
            acc[m][2] = __builtin_amdgcn_mfma_f32_16x16x32_bf16(a1[m], b1[2], acc[m][2], 0, 0, 0);
            acc[m][3] = __builtin_amdgcn_mfma_f32_16x16x32_bf16(a1[m], b1[3], acc[m][3], 0, 0, 0);
        }
        __builtin_amdgcn_s_setprio(0);
        __builtin_amdgcn_s_barrier();
    }
#undef STAGE_A8
#undef STAGE_B8

    // Epilogue. C/D layout: col = lane&15, row = (lane>>4)*4 + reg
    const long zC = (long)z * sC;
    const int colb = bx * 256 + wn * 64 + rr;
    const int rowb = by * 256 + wm * 128 + kq * 4;
#pragma unroll
    for (int m = 0; m < 8; ++m) {
#pragma unroll
        for (int n = 0; n < 4; ++n) {
            const int col = colb + n * 16;
            float bv = 0.0f;
            if constexpr (HAS_BIAS) bv = bias[col];
#pragma unroll
            for (int r = 0; r < 4; ++r) {
                const int row = rowb + m * 16 + r;
                float v = acc[m][n][r] * scale + bv;
                if constexpr (EXPW) v = __expf(v - 16.0f);
                if constexpr (RELU) v = v > 0.0f ? v : 0.0f;
                Cv[zC + (long)row * ldc + col] = f2b(v);
            }
        }
    }
}

// ---------------------------------------------------------------------------
// 128^2-tile GEMM (R8 structure) — kept for the 128-tile-count outputs:
// MODE 2: *rowinv[z*sR + row]    (ctx = P @ V, normalized)
// MODE 3: +bias, +resid(bf16)    (o-proj, FFN2)
// ---------------------------------------------------------------------------
template <int MODE, int BK>
__launch_bounds__(256, 2)
__global__ void gemm_bt(const unsigned short* __restrict__ A, int lda,
                        const unsigned short* __restrict__ Bt, int ldb,
                        unsigned short* __restrict__ Cv, int ldc,
                        const float* __restrict__ bias,
                        const unsigned short* __restrict__ resid, int ldr,
                        const float* __restrict__ rowinv,
                        int M, int N, int K,
                        long sA, long sB, long sC, long sR, float scale) {
    constexpr bool HAS_BIAS  = (MODE == 0 || MODE == 3 || MODE == 4);
    constexpr bool HAS_RESID = (MODE == 3);
    constexpr bool RELU      = (MODE == 4);
    constexpr bool EXPW      = (MODE == 1);
    constexpr bool ROWSCALE  = (MODE == 2);
    constexpr int  CPR = BK / 8;    // 16B chunks per row
    constexpr int  P   = BK / 16;   // staging groups of 256 chunks per operand
    constexpr int  KS  = BK / 32;   // 32-k steps per tile

    __shared__ unsigned short lds_us[256 * BK];  // A[128][BK] + B[128][BK]
    unsigned short* ldsA = lds_us;
    unsigned short* ldsB = lds_us + 128 * BK;

    const int nx = (int)gridDim.x, ny = (int)gridDim.y;
    int bx, by;
    if ((ny & 7) == 0) {
        const int n     = (int)blockIdx.y * nx + (int)blockIdx.x;
        const int xcd   = n & 7;
        const int slot  = n >> 3;
        const int bandh = ny >> 3;
        by = xcd * bandh + (slot % bandh);
        bx = slot / bandh;
    } else {
        bx = (int)blockIdx.x;
        by = (int)blockIdx.y;
    }

    const int z = blockIdx.z;
    const unsigned short* Ab = A + (long)z * sA + (long)by * 128 * lda;
    const unsigned short* Bb = Bt + (long)z * sB + (long)bx * 128 * ldb;

    const int tid  = threadIdx.x;
    const int lane = tid & 63;
    const int wid  = tid >> 6;
    const int wr   = wid >> 1;
    const int wc   = wid & 1;

    f32x4 acc[4][4] = {};

    long offA[P], offB[P];
    unsigned short* dA[P];
    unsigned short* dB[P];
#pragma unroll
    for (int p = 0; p < P; ++p) {
        const int s = p * 256 + tid;
        const int r = s / CPR;
        const int c = ((s & (CPR - 1)) ^ (r & (CPR - 1))) * 8;
        offA[p] = (long)r * lda + c;
        offB[p] = (long)r * ldb + c;
        dA[p] = ldsA + (p * 256 + wid * 64) * 8;
        dB[p] = ldsB + (p * 256 + wid * 64) * 8;
    }

    const int kq = lane >> 4;
    const int rr = lane & 15;

    for (int k0 = 0; k0 < K; k0 += BK) {
        __syncthreads();
#pragma unroll
        for (int p = 0; p < P; ++p) {
            async_copy16(Ab + offA[p] + k0, dA[p]);
            async_copy16(Bb + offB[p] + k0, dB[p]);
        }
        __syncthreads();

#pragma unroll
        for (int ks = 0; ks < KS; ++ks) {
            const int st = (ks * 4 + kq) ^ (rr & (CPR - 1));
            bf16x8 af[4], bfr[4];
#pragma unroll
            for (int mi = 0; mi < 4; ++mi)
                af[mi] = *(const bf16x8*)(ldsA + (wr * 64 + mi * 16 + rr) * BK + st * 8);
#pragma unroll
            for (int ni = 0; ni < 4; ++ni)
                bfr[ni] = *(const bf16x8*)(ldsB + (wc * 64 + ni * 16 + rr) * BK + st * 8);
#pragma unroll
            for (int mi = 0; mi < 4; ++mi)
#pragma unroll
                for (int ni = 0; ni < 4; ++ni)
                    acc[mi][ni] = __builtin_amdgcn_mfma_f32_16x16x32_bf16(af[mi], bfr[ni], acc[mi][ni], 0, 0, 0);
        }
    }

    const long zC = (long)z * sC;
    const int colb = bx * 128 + wc * 64 + rr;
    const int rowb = by * 128 + wr * 64 + kq * 4;
#pragma unroll
    for (int mi = 0; mi < 4; ++mi) {
#pragma unroll
        for (int ni = 0; ni < 4; ++ni) {
            const int col = colb + ni * 16;
            float bv = 0.0f;
            if constexpr (HAS_BIAS) bv = bias[col];
#pragma unroll
            for (int r = 0; r < 4; ++r) {
                const int row = rowb + mi * 16 + r;
                float v = acc[mi][ni][r] * scale + bv;
                if constexpr (EXPW) v = __expf(v - 16.0f);
                if constexpr (ROWSCALE) v *= rowinv[(long)z * sR + row];
                if constexpr (HAS_RESID) v += b2f(resid[(long)z * sR + (long)row * ldr + col]);
                if constexpr (RELU) v = v > 0.0f ? v : 0.0f;
                Cv[zC + (long)row * ldc + col] = f2b(v);
            }
        }
    }
}

// --------------------------- cast f32 -> bf16 ------------------------------
__global__ void cast_f32_bf16(const float* __restrict__ in, unsigned short* __restrict__ out, long n) {
    long i = ((long)blockIdx.x * 256 + threadIdx.x) * 4;
    if (i >= n) return;
    float4 v = *(const float4*)(in + i);
    ushort4 o;
    o.x = f2b(v.x); o.y = f2b(v.y); o.z = f2b(v.z); o.w = f2b(v.w);
    *(ushort4*)(out + i) = o;
}

// --------------------------- concat 3 bias vectors -------------------------
__global__ void concat3(const float* __restrict__ a, const float* __restrict__ b,
                        const float* __restrict__ c, float* __restrict__ o, int n) {
    int i = blockIdx.x * 256 + threadIdx.x;
    if (i < n) { o[i] = a[i]; o[i + n] = b[i]; o[i + 2 * n] = c[i]; }
}

// ------------------- transpose + cast f32[R][C] -> bf16[C][R] --------------
__global__ void transpose_cast(const float* __restrict__ src, unsigned short* __restrict__ dst,
                               int R, int C) {
    __shared__ float tile[32][33];
    const int bx = blockIdx.x * 32;
    const int by = blockIdx.y * 32;
    const int tx = threadIdx.x, ty = threadIdx.y;
#pragma unroll
    for (int i = 0; i < 32; i += 8)
        tile[ty + i][tx] = src[(long)(by + ty + i) * C + bx + tx];
    __syncthreads();
#pragma unroll
    for (int i = 0; i < 32; i += 8)
        dst[(long)(bx + ty + i) * R + by + tx] = f2b(tile[tx][ty + i]);
}

// ------ batched: 4 square f32[N][N] -> bf16[N][N]^T, dst contiguous --------
__global__ void transpose_cast4(const float* __restrict__ s0, const float* __restrict__ s1,
                                const float* __restrict__ s2, const float* __restrict__ s3,
                                unsigned short* __restrict__ dst, int N) {
    const float* src = (blockIdx.z == 0) ? s0 : (blockIdx.z == 1) ? s1 : (blockIdx.z == 2) ? s2 : s3;
    unsigned short* d = dst + (long)blockIdx.z * N * N;
    __shared__ float tile[32][33];
    const int bx = blockIdx.x * 32;
    const int by = blockIdx.y * 32;
    const int tx = threadIdx.x, ty = threadIdx.y;
#pragma unroll
    for (int i = 0; i < 32; i += 8)
        tile[ty + i][tx] = src[(long)(by + ty + i) * N + bx + tx];
    __syncthreads();
#pragma unroll
    for (int i = 0; i < 32; i += 8)
        d[(long)(bx + ty + i) * N + by + tx] = f2b(tile[tx][ty + i]);
}

// -------- transpose bf16 [R][C] (row stride ld) -> [C][R], batched ---------
__global__ void transpose_bf16(const unsigned short* __restrict__ src, long sS, int ld,
                               unsigned short* __restrict__ dst, long sD, int R, int C) {
    const int z = blockIdx.z;
    src += (long)z * sS;
    dst += (long)z * sD;
    __shared__ unsigned short tile[32][33];
    const int bx = blockIdx.x * 32;
    const int by = blockIdx.y * 32;
    const int tx = threadIdx.x, ty = threadIdx.y;
#pragma unroll
    for (int i = 0; i < 32; i += 8)
        tile[ty + i][tx] = src[(long)(by + ty + i) * ld + bx + tx];
    __syncthreads();
#pragma unroll
    for (int i = 0; i < 32; i += 8)
        dst[(long)(bx + ty + i) * R + by + tx] = tile[tx][ty + i];
}

// ---- rowsum of bf16 matrix rows (2048 cols) -> 1/sum (fp32) per row -------
__global__ void rowsum_inv(const unsigned short* __restrict__ P, float* __restrict__ inv) {
    const long row = blockIdx.x;
    const ushort4* pr = (const ushort4*)(P + row * 2048);
    const int t = threadIdx.x;
    ushort4 a = pr[t];
    ushort4 b = pr[t + 256];
    float s = b2f(a.x) + b2f(a.y) + b2f(a.z) + b2f(a.w)
            + b2f(b.x) + b2f(b.y) + b2f(b.z) + b2f(b.w);
#pragma unroll
    for (int off = 32; off > 0; off >>= 1) s += __shfl_down(s, off);
    __shared__ float red[4];
    if ((t & 63) == 0) red[t >> 6] = s;
    __syncthreads();
    if (t == 0) inv[row] = 1.0f / (red[0] + red[1] + red[2] + red[3]);
}

// ------------------ LayerNorm (1024 cols), bf16 input ----------------------
template <bool OUT_F32>
__global__ void layernorm_bf16(const unsigned short* __restrict__ in, float* outf,
                               unsigned short* outb,
                               const float* __restrict__ g, const float* __restrict__ b) {
    const long row = blockIdx.x;
    const int t = threadIdx.x;
    const ushort4 u = ((const ushort4*)(in + row * 1024))[t];
    float4 v;
    v.x = b2f(u.x); v.y = b2f(u.y); v.z = b2f(u.z); v.w = b2f(u.w);
    float s = v.x + v.y + v.z + v.w;
    float q = v.x * v.x + v.y * v.y + v.z * v.z + v.w * v.w;
#pragma unroll
    for (int off = 32; off > 0; off >>= 1) {
        s += __shfl_down(s, off);
        q += __shfl_down(q, off);
    }
    __shared__ float red[8];
    if ((t & 63) == 0) { red[t >> 6] = s; red[4 + (t >> 6)] = q; }
    __syncthreads();
    s = red[0] + red[1] + red[2] + red[3];
    q = red[4] + red[5] + red[6] + red[7];
    const float mean = s * (1.0f / 1024.0f);
    const float var  = q * (1.0f / 1024.0f) - mean * mean;
    const float inv  = rsqrtf(var + 1e-5f);
    const float4 gg = ((const float4*)g)[t];
    const float4 bb = ((const float4*)b)[t];
    float4 o;
    o.x = (v.x - mean) * inv * gg.x + bb.x;
    o.y = (v.y - mean) * inv * gg.y + bb.y;
    o.z = (v.z - mean) * inv * gg.z + bb.z;
    o.w = (v.w - mean) * inv * gg.w + bb.w;
    if constexpr (OUT_F32) {
        ((float4*)(outf + row * 1024))[t] = o;
    } else {
        ushort4 ob;
        ob.x = f2b(o.x); ob.y = f2b(o.y); ob.z = f2b(o.z); ob.w = f2b(o.w);
        ((ushort4*)(outb + row * 1024))[t] = ob;
    }
}

// ---------------------------------------------------------------------------
extern "C" void kernel_launch(void* const* d_in, const int* in_sizes, int n_in,
                              void* d_out, int out_size, void* d_ws, size_t ws_size,
                              hipStream_t stream) {
    (void)in_sizes; (void)n_in; (void)out_size; (void)ws_size;
    const float* x   = (const float*)d_in[0];
    const float* wq  = (const float*)d_in[1];
    const float* bq  = (const float*)d_in[2];
    const float* wk  = (const float*)d_in[3];
    const float* bk  = (const float*)d_in[4];
    const float* wv  = (const float*)d_in[5];
    const float* bv  = (const float*)d_in[6];
    const float* wo  = (const float*)d_in[7];
    const float* bo  = (const float*)d_in[8];
    const float* w1  = (const float*)d_in[9];
    const float* b1  = (const float*)d_in[10];
    const float* w2  = (const float*)d_in[11];
    const float* b2  = (const float*)d_in[12];
    const float* g1  = (const float*)d_in[13];
    const float* be1 = (const float*)d_in[14];
    const float* g2  = (const float*)d_in[15];
    const float* be2 = (const float*)d_in[16];

    const int D = 1024, FF = 4096, T = 2048, M = 8192;
    const size_t MB = 1ull << 20;
    char* w = (char*)d_ws;
    unsigned short* wqT = (unsigned short*)(w + 0 * MB);    // [3072][1024] wcat
    unsigned short* woT = (unsigned short*)(w + 6 * MB);    // [1024][1024]
    unsigned short* w1T = (unsigned short*)(w + 8 * MB);    // [4096][1024]
    unsigned short* w2T = (unsigned short*)(w + 16 * MB);   // [1024][4096]
    unsigned short* xb  = (unsigned short*)(w + 24 * MB);   // [8192][1024]
    unsigned short* qkv = (unsigned short*)(w + 40 * MB);   // [8192][3072]
    float*          rsum = (float*)(w + 40 * MB);           // [8192] aliases dead q-part
    float*          bcat = (float*)(w + 88 * MB);           // [3072]
    unsigned short* vT  = (unsigned short*)(w + 88 * MB);   // [4][1024][2048]
    unsigned short* pr  = (unsigned short*)(w + 104 * MB);  // [4][2048][2048] bf16
    unsigned short* ctxb = (unsigned short*)(w + 136 * MB); // [8192][1024] bf16
    unsigned short* t0  = (unsigned short*)(w + 152 * MB);  // [8192][1024] bf16
    unsigned short* x1b = (unsigned short*)(w + 56 * MB);   // [8192][1024] bf16
    unsigned short* h   = (unsigned short*)(w + 88 * MB);   // [8192][4096] bf16
    unsigned short* y   = (unsigned short*)(w + 168 * MB);  // [8192][1024] bf16

    const dim3 tb(32, 8);
    transpose_cast4<<<dim3(32, 32, 4), tb, 0, stream>>>(wq, wk, wv, wo, wqT, D);
    transpose_cast<<<dim3(128, 32), tb, 0, stream>>>(w1, w1T, D, FF);
    transpose_cast<<<dim3(32, 128), tb, 0, stream>>>(w2, w2T, FF, D);
    concat3<<<4, 256, 0, stream>>>(bq, bk, bv, bcat, D);
    cast_f32_bf16<<<8192, 256, 0, stream>>>(x, xb, (long)M * D);

    // Fused QKV projection (8-phase 256^2): [8192][3072] = xb @ wcat^T + bcat
    gemm8<0><<<dim3(12, 32, 1), 512, 0, stream>>>(xb, D, wqT, D, qkv, 3 * D, bcat,
                                                  M, 3 * D, D, 0, 0, 0, 1.0f);

    // V transpose per batch: view [2048][1024] (stride 3072) -> [1024][2048]
    transpose_bf16<<<dim3(32, 64, 4), tb, 0, stream>>>(qkv + 2 * D, (long)T * 3 * D, 3 * D,
                                                       vT, (long)D * T, T, D);

    // P = exp(q @ k^T / sqrt(128) - 16), bf16 unnormalized (8-phase 256^2)
    gemm8<1><<<dim3(8, 8, 4), 512, 0, stream>>>(qkv, 3 * D, qkv + D, 3 * D, pr, T,
                                                nullptr, T, T, D,
                                                (long)T * 3 * D, (long)T * 3 * D, (long)T * T,
                                                0.08838834764831845f);
    rowsum_inv<<<8192, 256, 0, stream>>>(pr, rsum);

    // ctx = (P @ v) * rowinv   (128 output 256-tiles -> keep 128^2 kernel)
    gemm_bt<2, 128><<<dim3(8, 16, 4), 256, 0, stream>>>(pr, T, vT, T, ctxb, D,
                                                        nullptr, nullptr, 0, rsum, T, D, T,
                                                        (long)T * T, (long)D * T, (long)T * D, T, 1.0f);

    // o-projection + residual (bf16 xb), bf16 out (128^2 kernel)
    gemm_bt<3, 128><<<dim3(8, 64, 1), 256, 0, stream>>>(ctxb, D, woT, D, t0, D, bo, xb, D,
                                                        nullptr, M, D, D, 0, 0, 0, 0, 1.0f);

    // LN1 (bf16 in) -> bf16 x1b (FFN input + FFN2 residual)
    layernorm_bf16<false><<<8192, 256, 0, stream>>>(t0, nullptr, x1b, g1, be1);

    // FFN1 (8-phase 256^2): [8192][4096]
    gemm8<4><<<dim3(16, 32, 1), 512, 0, stream>>>(x1b, D, w1T, D, h, FF, b1,
                                                  M, FF, D, 0, 0, 0, 1.0f);
    // FFN2 (128^2 kernel, K=4096)
    gemm_bt<3, 128><<<dim3(8, 64, 1), 256, 0, stream>>>(h, FF, w2T, FF, y, D, b2, x1b, D,
                                                        nullptr, M, D, FF, 0, 0, 0, 0, 1.0f);

    // LN2 (bf16 in) -> output (fp32)
    layernorm_bf16<true><<<8192, 256, 0, stream>>>(y, (float*)d_out, nullptr, g2, be2);
}

// Round 4
// 500.367 us; speedup vs baseline: 1.0625x; 1.0625x over previous
//
#include <hip/hip_runtime.h>
#include <hip/hip_bf16.h>
#include <stdint.h>

// ---------------------------------------------------------------------------
// SmallTransformerBlock on MI355X (gfx950)  — Round 12
//   B=4, T=2048, D=1024, FF=4096, full-D attention, scale = sqrt(128)
// R11 -> R12 (bank measured wins, drop speculative pipelining):
//   * gemm8 body reverted to the R10 schedule (in-phase reads, lgkm(0),
//     vmcnt(4) at P4/P8). R11's read-ahead spilled (VGPR 128 + 10MiB
//     scratch writes/dispatch) and regressed 76.8 -> 86.8 us.
//   * FFN1 back to gemm_bt<4,64> (direct A/B: 71.5 us vs gemm8's 76.8).
//     QKV + scores stay on gemm8 (R0->R2 bundle delta -17 us).
//   * rowsum fused into scores epilogue: fp32 partial sums + shfl_xor
//     reduce + atomicAdd into zeroed rsum; ctx multiplies by 1/rsum.
//     Deletes rowsum_inv kernel (32 MiB re-read + launch). rsum aliases
//     t0 (disjoint lifetimes: rsum dies at ctx, t0 born at oproj) and is
//     zeroed inside transpose_cast4 (first kernel).
// ---------------------------------------------------------------------------

typedef __bf16 bf16x8 __attribute__((ext_vector_type(8)));
typedef float f32x4 __attribute__((ext_vector_type(4)));

__device__ __forceinline__ unsigned short f2b(float f) {
    __hip_bfloat16 h = __float2bfloat16(f);
    unsigned short u;
    __builtin_memcpy(&u, &h, 2);
    return u;
}

__device__ __forceinline__ float b2f(unsigned short u) {
    __hip_bfloat16 h;
    __builtin_memcpy(&h, &u, 2);
    return __bfloat162float(h);
}

__device__ __forceinline__ void async_copy16(const unsigned short* g, unsigned short* l) {
    __builtin_amdgcn_global_load_lds((__attribute__((address_space(1))) void*)(g),
                                     (__attribute__((address_space(3))) void*)(l),
                                     16, 0, 0);
}

// ---------------------------------------------------------------------------
// gemm8: C[M,N] = A[M,K] @ Bt[N,K]^T, 256x256 tile, BK=64, 8-phase schedule
// (R10 body — measured 469.9us wall config).
// MODE 0: +bias   MODE 1: exp(acc*scale-16) + fused row-sum atomicAdd
// grid = (N/256, M/256, batch), block = 512. Requires K % 128 == 0.
// ---------------------------------------------------------------------------
template <int MODE>
__launch_bounds__(512, 2)
__global__ void gemm8(const unsigned short* __restrict__ A, int lda,
                      const unsigned short* __restrict__ Bt, int ldb,
                      unsigned short* __restrict__ Cv, int ldc,
                      const float* __restrict__ bias,
                      float* __restrict__ rsum, long sRs,
                      int M, int N, int K,
                      long sA, long sB, long sC, float scale) {
    constexpr bool HAS_BIAS = (MODE == 0);
    constexpr bool EXPW     = (MODE == 1);

    __shared__ unsigned short lds8[65536];  // 128 KiB: [buf][A 16384 | B 16384]

    // XCD-aware swizzle (nwg % 8 == 0 for all our grids)
    const int nx = (int)gridDim.x, ny = (int)gridDim.y;
    int bx, by;
    if ((ny & 7) == 0) {
        const int n     = (int)blockIdx.y * nx + (int)blockIdx.x;
        const int xcd   = n & 7;
        const int slot  = n >> 3;
        const int bandh = ny >> 3;
        by = xcd * bandh + (slot % bandh);
        bx = slot / bandh;
    } else {
        bx = (int)blockIdx.x;
        by = (int)blockIdx.y;
    }

    const int z = blockIdx.z;
    const unsigned short* Ab = A + (long)z * sA + (long)by * 256 * lda;
    const unsigned short* Bb = Bt + (long)z * sB + (long)bx * 256 * ldb;

    const int tid  = threadIdx.x;
    const int lane = tid & 63;
    const int wid  = tid >> 6;
    const int wm   = wid >> 2;   // 0..1 -> 128 rows
    const int wn   = wid & 3;    // 0..3 -> 64 cols
    const int rr   = lane & 15;
    const int kq   = lane >> 4;
    const int s7   = rr & 7;
    const int cK0  = (kq ^ s7) * 8;         // swizzled chunk offset, ks=0
    const int cK1  = ((4 | kq) ^ s7) * 8;   // ks=1

    // staging: 1024 chunks per half-tile, 2 calls x 512 threads.
    // LDS slot (r, c) holds global chunk c ^ (r&7)  [XOR swizzle; read side
    // applies the same XOR -> conflict-free, 0 conflicts measured]
    long offA[2], offB[2];
    int dstp[2];
#pragma unroll
    for (int j = 0; j < 2; ++j) {
        const int s = j * 512 + tid;
        const int r = s >> 3;
        const int c = ((s & 7) ^ (r & 7)) * 8;
        offA[j] = (long)r * lda + c;
        offB[j] = (long)r * ldb + c;
        dstp[j] = (j * 512 + wid * 64) * 8;   // elems; HW adds lane*16B
    }

#define STAGE_A8(buf, half, kt) do {                                          \
    const unsigned short* _s = Ab + (long)(half) * 128 * lda + ((kt) << 6);   \
    unsigned short* _d = lds8 + (buf) * 32768 + (half) * 8192;                \
    async_copy16(_s + offA[0], _d + dstp[0]);                                 \
    async_copy16(_s + offA[1], _d + dstp[1]);                                 \
} while (0)
#define STAGE_B8(buf, half, kt) do {                                          \
    const unsigned short* _s = Bb + (long)(half) * 128 * ldb + ((kt) << 6);   \
    unsigned short* _d = lds8 + (buf) * 32768 + 16384 + (half) * 8192;        \
    async_copy16(_s + offB[0], _d + dstp[0]);                                 \
    async_copy16(_s + offB[1], _d + dstp[1]);                                 \
} while (0)

    const int nt = K >> 6;   // K-tiles (even; K % 128 == 0)

    f32x4 acc[8][4] = {};
    bf16x8 a0[8], a1[8], b0[4], b1[4];

    // prologue: tile0 -> buf0 (Bh0 Ah0 Bh1 Ah1), tile1 -> buf1 (Bh0 Ah0)
    STAGE_B8(0, 0, 0); STAGE_A8(0, 0, 0); STAGE_B8(0, 1, 0); STAGE_A8(0, 1, 0);
    STAGE_B8(1, 0, 1); STAGE_A8(1, 0, 1);
    asm volatile("s_waitcnt vmcnt(4)" ::: "memory");   // tile0 resident
    __builtin_amdgcn_s_barrier();

    const int aRow = wm * 128 + rr;
    const int bRow = wn * 64 + rr;
    const unsigned short* lA0 = lds8;
    const unsigned short* lB0 = lds8 + 16384;
    const unsigned short* lA1 = lds8 + 32768;
    const unsigned short* lB1 = lds8 + 32768 + 16384;

    for (int it = 0; it < (nt >> 1); ++it) {
        const int t = it * 2;
        int t2 = t + 2; if (t2 >= nt) t2 -= nt;   // wrapped stages at the
        int t3 = t + 3; if (t3 >= nt) t3 -= nt;   // tail are harmless (WAR-safe)

        // ---- P1: read buf0 ks0 (A m0-7, B n0-3); stage (t+1).Bh1 -> buf1
#pragma unroll
        for (int m = 0; m < 8; ++m) a0[m] = *(const bf16x8*)(lA0 + (aRow + m * 16) * 64 + cK0);
#pragma unroll
        for (int n = 0; n < 4; ++n) b0[n] = *(const bf16x8*)(lB0 + (bRow + n * 16) * 64 + cK0);
        STAGE_B8(1, 1, t + 1);
        __builtin_amdgcn_s_barrier();
        asm volatile("s_waitcnt lgkmcnt(0)" ::: "memory");
        __builtin_amdgcn_sched_barrier(0);
        __builtin_amdgcn_s_setprio(1);
#pragma unroll
        for (int m = 0; m < 8; ++m) {
            acc[m][0] = __builtin_amdgcn_mfma_f32_16x16x32_bf16(a0[m], b0[0], acc[m][0], 0, 0, 0);
            acc[m][1] = __builtin_amdgcn_mfma_f32_16x16x32_bf16(a0[m], b0[1], acc[m][1], 0, 0, 0);
        }
        __builtin_amdgcn_s_setprio(0);
        __builtin_amdgcn_s_barrier();

        // ---- P2: read buf0 B ks1; stage (t+1).Ah1 -> buf1
#pragma unroll
        for (int n = 0; n < 4; ++n) b1[n] = *(const bf16x8*)(lB0 + (bRow + n * 16) * 64 + cK1);
        STAGE_A8(1, 1, t + 1);
        __builtin_amdgcn_s_barrier();
        asm volatile("s_waitcnt lgkmcnt(0)" ::: "memory");
        __builtin_amdgcn_sched_barrier(0);
        __builtin_amdgcn_s_setprio(1);
#pragma unroll
        for (int m = 0; m < 8; ++m) {
            acc[m][2] = __builtin_amdgcn_mfma_f32_16x16x32_bf16(a0[m], b0[2], acc[m][2], 0, 0, 0);
            acc[m][3] = __builtin_amdgcn_mfma_f32_16x16x32_bf16(a0[m], b0[3], acc[m][3], 0, 0, 0);
        }
        __builtin_amdgcn_s_setprio(0);
        __builtin_amdgcn_s_barrier();

        // ---- P3: read buf0 A ks1; stage (t+2).Bh0 -> buf0 (B free after P2)
#pragma unroll
        for (int m = 0; m < 8; ++m) a1[m] = *(const bf16x8*)(lA0 + (aRow + m * 16) * 64 + cK1);
        STAGE_B8(0, 0, t2);
        __builtin_amdgcn_s_barrier();
        asm volatile("s_waitcnt lgkmcnt(0)" ::: "memory");
        __builtin_amdgcn_sched_barrier(0);
        __builtin_amdgcn_s_setprio(1);
#pragma unroll
        for (int m = 0; m < 8; ++m) {
            acc[m][0] = __builtin_amdgcn_mfma_f32_16x16x32_bf16(a1[m], b1[0], acc[m][0], 0, 0, 0);
            acc[m][1] = __builtin_amdgcn_mfma_f32_16x16x32_bf16(a1[m], b1[1], acc[m][1], 0, 0, 0);
        }
        __builtin_amdgcn_s_setprio(0);
        __builtin_amdgcn_s_barrier();

        // ---- P4: stage (t+2).Ah0 -> buf0 (A free after P3); vmcnt(4) boundary
        STAGE_A8(0, 0, t2);
        __builtin_amdgcn_s_barrier();
        __builtin_amdgcn_s_setprio(1);
#pragma unroll
        for (int m = 0; m < 8; ++m) {
            acc[m][2] = __builtin_amdgcn_mfma_f32_16x16x32_bf16(a1[m], b1[2], acc[m][2], 0, 0, 0);
            acc[m][3] = __builtin_amdgcn_mfma_f32_16x16x32_bf16(a1[m], b1[3], acc[m][3], 0, 0, 0);
        }
        __builtin_amdgcn_s_setprio(0);
        asm volatile("s_waitcnt vmcnt(4)" ::: "memory");  // tile t+1 resident
        __builtin_amdgcn_s_barrier();

        // ---- P5: read buf1 ks0; stage (t+2).Bh1 -> buf0
#pragma unroll
        for (int m = 0; m < 8; ++m) a0[m] = *(const bf16x8*)(lA1 + (aRow + m * 16) * 64 + cK0);
#pragma unroll
        for (int n = 0; n < 4; ++n) b0[n] = *(const bf16x8*)(lB1 + (bRow + n * 16) * 64 + cK0);
        STAGE_B8(0, 1, t2);
        __builtin_amdgcn_s_barrier();
        asm volatile("s_waitcnt lgkmcnt(0)" ::: "memory");
        __builtin_amdgcn_sched_barrier(0);
        __builtin_amdgcn_s_setprio(1);
#pragma unroll
        for (int m = 0; m < 8; ++m) {
            acc[m][0] = __builtin_amdgcn_mfma_f32_16x16x32_bf16(a0[m], b0[0], acc[m][0], 0, 0, 0);
            acc[m][1] = __builtin_amdgcn_mfma_f32_16x16x32_bf16(a0[m], b0[1], acc[m][1], 0, 0, 0);
        }
        __builtin_amdgcn_s_setprio(0);
        __builtin_amdgcn_s_barrier();

        // ---- P6: read buf1 B ks1; stage (t+2).Ah1 -> buf0
#pragma unroll
        for (int n = 0; n < 4; ++n) b1[n] = *(const bf16x8*)(lB1 + (bRow + n * 16) * 64 + cK1);
        STAGE_A8(0, 1, t2);
        __builtin_amdgcn_s_barrier();
        asm volatile("s_waitcnt lgkmcnt(0)" ::: "memory");
        __builtin_amdgcn_sched_barrier(0);
        __builtin_amdgcn_s_setprio(1);
#pragma unroll
        for (int m = 0; m < 8; ++m) {
            acc[m][2] = __builtin_amdgcn_mfma_f32_16x16x32_bf16(a0[m], b0[2], acc[m][2], 0, 0, 0);
            acc[m][3] = __builtin_amdgcn_mfma_f32_16x16x32_bf16(a0[m], b0[3], acc[m][3], 0, 0, 0);
        }
        __builtin_amdgcn_s_setprio(0);
        __builtin_amdgcn_s_barrier();

        // ---- P7: read buf1 A ks1; stage (t+3).Bh0 -> buf1 (B free after P6)
#pragma unroll
        for (int m = 0; m < 8; ++m) a1[m] = *(const bf16x8*)(lA1 + (aRow + m * 16) * 64 + cK1);
        STAGE_B8(1, 0, t3);
        __builtin_amdgcn_s_barrier();
        asm volatile("s_waitcnt lgkmcnt(0)" ::: "memory");
        __builtin_amdgcn_sched_barrier(0);
        __builtin_amdgcn_s_setprio(1);
#pragma unroll
        for (int m = 0; m < 8; ++m) {
            acc[m][0] = __builtin_amdgcn_mfma_f32_16x16x32_bf16(a1[m], b1[0], acc[m][0], 0, 0, 0);
            acc[m][1] = __builtin_amdgcn_mfma_f32_16x16x32_bf16(a1[m], b1[1], acc[m][1], 0, 0, 0);
        }
        __builtin_amdgcn_s_setprio(0);
        __builtin_amdgcn_s_barrier();

        // ---- P8: stage (t+3).Ah0 -> buf1 (A free after P7); vmcnt(4) boundary
        STAGE_A8(1, 0, t3);
        __builtin_amdgcn_s_barrier();
        __builtin_amdgcn_s_setprio(1);
#pragma unroll
        for (int m = 0; m < 8; ++m) {
            acc[m][2] = __builtin_amdgcn_mfma_f32_16x16x32_bf16(a1[m], b1[2], acc[m][2], 0, 0, 0);
            acc[m][3] = __builtin_amdgcn_mfma_f32_16x16x32_bf16(a1[m], b1[3], acc[m][3], 0, 0, 0);
        }
        __builtin_amdgcn_s_setprio(0);
        asm volatile("s_waitcnt vmcnt(4)" ::: "memory");  // tile t+2 resident
        __builtin_amdgcn_s_barrier();
    }
#undef STAGE_A8
#undef STAGE_B8

    // Epilogue. C/D layout: col = lane&15, row = (lane>>4)*4 + reg
    const long zC = (long)z * sC;
    const int colb = bx * 256 + wn * 64 + rr;
    const int rowb = by * 256 + wm * 128 + kq * 4;
    if constexpr (EXPW) {
        // exp epilogue + fused row-sum: per (m,r) the wave's 16 rr-lanes x
        // 4 n-frags cover 64 cols of one row. Partial-sum fp32, shfl_xor
        // reduce over rr, one atomicAdd per row per wave.
#pragma unroll
        for (int m = 0; m < 8; ++m) {
#pragma unroll
            for (int r = 0; r < 4; ++r) {
                const int row = rowb + m * 16 + r;
                float part = 0.0f;
#pragma unroll
                for (int n = 0; n < 4; ++n) {
                    const int col = colb + n * 16;
                    float v = __expf(acc[m][n][r] * scale - 16.0f);
                    part += v;
                    Cv[zC + (long)row * ldc + col] = f2b(v);
                }
                part += __shfl_xor(part, 1);
                part += __shfl_xor(part, 2);
                part += __shfl_xor(part, 4);
                part += __shfl_xor(part, 8);
                if (rr == 0) atomicAdd(&rsum[(long)z * sRs + row], part);
            }
        }
    } else {
#pragma unroll
        for (int m = 0; m < 8; ++m) {
#pragma unroll
            for (int n = 0; n < 4; ++n) {
                const int col = colb + n * 16;
                float bv = 0.0f;
                if constexpr (HAS_BIAS) bv = bias[col];
#pragma unroll
                for (int r = 0; r < 4; ++r) {
                    const int row = rowb + m * 16 + r;
                    float v = acc[m][n][r] * scale + bv;
                    Cv[zC + (long)row * ldc + col] = f2b(v);
                }
            }
        }
    }
}

// ---------------------------------------------------------------------------
// 128^2-tile GEMM (R8 structure) — the workhorse:
// MODE 2: /rsum[z*sR + row]      (ctx = P @ V, normalized by fused rowsum)
// MODE 3: +bias, +resid(bf16)    (o-proj, FFN2)
// MODE 4: +bias, relu            (FFN1)
// ---------------------------------------------------------------------------
template <int MODE, int BK>
__launch_bounds__(256, 2)
__global__ void gemm_bt(const unsigned short* __restrict__ A, int lda,
                        const unsigned short* __restrict__ Bt, int ldb,
                        unsigned short* __restrict__ Cv, int ldc,
                        const float* __restrict__ bias,
                        const unsigned short* __restrict__ resid, int ldr,
                        const float* __restrict__ rowsum,
                        int M, int N, int K,
                        long sA, long sB, long sC, long sR, float scale) {
    constexpr bool HAS_BIAS  = (MODE == 0 || MODE == 3 || MODE == 4);
    constexpr bool HAS_RESID = (MODE == 3);
    constexpr bool RELU      = (MODE == 4);
    constexpr bool ROWSCALE  = (MODE == 2);
    constexpr int  CPR = BK / 8;    // 16B chunks per row
    constexpr int  P   = BK / 16;   // staging groups of 256 chunks per operand
    constexpr int  KS  = BK / 32;   // 32-k steps per tile

    __shared__ unsigned short lds_us[256 * BK];  // A[128][BK] + B[128][BK]
    unsigned short* ldsA = lds_us;
    unsigned short* ldsB = lds_us + 128 * BK;

    const int nx = (int)gridDim.x, ny = (int)gridDim.y;
    int bx, by;
    if ((ny & 7) == 0) {
        const int n     = (int)blockIdx.y * nx + (int)blockIdx.x;
        const int xcd   = n & 7;
        const int slot  = n >> 3;
        const int bandh = ny >> 3;
        by = xcd * bandh + (slot % bandh);
        bx = slot / bandh;
    } else {
        bx = (int)blockIdx.x;
        by = (int)blockIdx.y;
    }

    const int z = blockIdx.z;
    const unsigned short* Ab = A + (long)z * sA + (long)by * 128 * lda;
    const unsigned short* Bb = Bt + (long)z * sB + (long)bx * 128 * ldb;

    const int tid  = threadIdx.x;
    const int lane = tid & 63;
    const int wid  = tid >> 6;
    const int wr   = wid >> 1;
    const int wc   = wid & 1;

    f32x4 acc[4][4] = {};

    long offA[P], offB[P];
    unsigned short* dA[P];
    unsigned short* dB[P];
#pragma unroll
    for (int p = 0; p < P; ++p) {
        const int s = p * 256 + tid;
        const int r = s / CPR;
        const int c = ((s & (CPR - 1)) ^ (r & (CPR - 1))) * 8;
        offA[p] = (long)r * lda + c;
        offB[p] = (long)r * ldb + c;
        dA[p] = ldsA + (p * 256 + wid * 64) * 8;
        dB[p] = ldsB + (p * 256 + wid * 64) * 8;
    }

    const int kq = lane >> 4;
    const int rr = lane & 15;

    for (int k0 = 0; k0 < K; k0 += BK) {
        __syncthreads();
#pragma unroll
        for (int p = 0; p < P; ++p) {
            async_copy16(Ab + offA[p] + k0, dA[p]);
            async_copy16(Bb + offB[p] + k0, dB[p]);
        }
        __syncthreads();

#pragma unroll
        for (int ks = 0; ks < KS; ++ks) {
            const int st = (ks * 4 + kq) ^ (rr & (CPR - 1));
            bf16x8 af[4], bfr[4];
#pragma unroll
            for (int mi = 0; mi < 4; ++mi)
                af[mi] = *(const bf16x8*)(ldsA + (wr * 64 + mi * 16 + rr) * BK + st * 8);
#pragma unroll
            for (int ni = 0; ni < 4; ++ni)
                bfr[ni] = *(const bf16x8*)(ldsB + (wc * 64 + ni * 16 + rr) * BK + st * 8);
#pragma unroll
            for (int mi = 0; mi < 4; ++mi)
#pragma unroll
                for (int ni = 0; ni < 4; ++ni)
                    acc[mi][ni] = __builtin_amdgcn_mfma_f32_16x16x32_bf16(af[mi], bfr[ni], acc[mi][ni], 0, 0, 0);
        }
    }

    const long zC = (long)z * sC;
    const int colb = bx * 128 + wc * 64 + rr;
    const int rowb = by * 128 + wr * 64 + kq * 4;
#pragma unroll
    for (int mi = 0; mi < 4; ++mi) {
        float inv_r[4];
        if constexpr (ROWSCALE) {
#pragma unroll
            for (int r = 0; r < 4; ++r)
                inv_r[r] = 1.0f / rowsum[(long)z * sR + (rowb + mi * 16 + r)];
        }
#pragma unroll
        for (int ni = 0; ni < 4; ++ni) {
            const int col = colb + ni * 16;
            float bv = 0.0f;
            if constexpr (HAS_BIAS) bv = bias[col];
#pragma unroll
            for (int r = 0; r < 4; ++r) {
                const int row = rowb + mi * 16 + r;
                float v = acc[mi][ni][r] * scale + bv;
                if constexpr (ROWSCALE) v *= inv_r[r];
                if constexpr (HAS_RESID) v += b2f(resid[(long)z * sR + (long)row * ldr + col]);
                if constexpr (RELU) v = v > 0.0f ? v : 0.0f;
                Cv[zC + (long)row * ldc + col] = f2b(v);
            }
        }
    }
}

// --------------------------- cast f32 -> bf16 ------------------------------
__global__ void cast_f32_bf16(const float* __restrict__ in, unsigned short* __restrict__ out, long n) {
    long i = ((long)blockIdx.x * 256 + threadIdx.x) * 4;
    if (i >= n) return;
    float4 v = *(const float4*)(in + i);
    ushort4 o;
    o.x = f2b(v.x); o.y = f2b(v.y); o.z = f2b(v.z); o.w = f2b(v.w);
    *(ushort4*)(out + i) = o;
}

// --------------------------- concat 3 bias vectors -------------------------
__global__ void concat3(const float* __restrict__ a, const float* __restrict__ b,
                        const float* __restrict__ c, float* __restrict__ o, int n) {
    int i = blockIdx.x * 256 + threadIdx.x;
    if (i < n) { o[i] = a[i]; o[i + n] = b[i]; o[i + 2 * n] = c[i]; }
}

// ------------------- transpose + cast f32[R][C] -> bf16[C][R] --------------
__global__ void transpose_cast(const float* __restrict__ src, unsigned short* __restrict__ dst,
                               int R, int C) {
    __shared__ float tile[32][33];
    const int bx = blockIdx.x * 32;
    const int by = blockIdx.y * 32;
    const int tx = threadIdx.x, ty = threadIdx.y;
#pragma unroll
    for (int i = 0; i < 32; i += 8)
        tile[ty + i][tx] = src[(long)(by + ty + i) * C + bx + tx];
    __syncthreads();
#pragma unroll
    for (int i = 0; i < 32; i += 8)
        dst[(long)(bx + ty + i) * R + by + tx] = f2b(tile[tx][ty + i]);
}

// ------ batched: 4 square f32[N][N] -> bf16[N][N]^T; also zeroes rsum ------
__global__ void transpose_cast4(const float* __restrict__ s0, const float* __restrict__ s1,
                                const float* __restrict__ s2, const float* __restrict__ s3,
                                unsigned short* __restrict__ dst, int N,
                                float* __restrict__ rz, int nrz) {
    if (blockIdx.z == 0) {
        const int gid = ((int)blockIdx.y * (int)gridDim.x + (int)blockIdx.x) * 256
                      + (int)threadIdx.y * 32 + (int)threadIdx.x;
        if (gid < nrz) rz[gid] = 0.0f;
    }
    const float* src = (blockIdx.z == 0) ? s0 : (blockIdx.z == 1) ? s1 : (blockIdx.z == 2) ? s2 : s3;
    unsigned short* d = dst + (long)blockIdx.z * N * N;
    __shared__ float tile[32][33];
    const int bx = blockIdx.x * 32;
    const int by = blockIdx.y * 32;
    const int tx = threadIdx.x, ty = threadIdx.y;
#pragma unroll
    for (int i = 0; i < 32; i += 8)
        tile[ty + i][tx] = src[(long)(by + ty + i) * N + bx + tx];
    __syncthreads();
#pragma unroll
    for (int i = 0; i < 32; i += 8)
        d[(long)(bx + ty + i) * N + by + tx] = f2b(tile[tx][ty + i]);
}

// -------- transpose bf16 [R][C] (row stride ld) -> [C][R], batched ---------
__global__ void transpose_bf16(const unsigned short* __restrict__ src, long sS, int ld,
                               unsigned short* __restrict__ dst, long sD, int R, int C) {
    const int z = blockIdx.z;
    src += (long)z * sS;
    dst += (long)z * sD;
    __shared__ unsigned short tile[32][33];
    const int bx = blockIdx.x * 32;
    const int by = blockIdx.y * 32;
    const int tx = threadIdx.x, ty = threadIdx.y;
#pragma unroll
    for (int i = 0; i < 32; i += 8)
        tile[ty + i][tx] = src[(long)(by + ty + i) * ld + bx + tx];
    __syncthreads();
#pragma unroll
    for (int i = 0; i < 32; i += 8)
        dst[(long)(bx + ty + i) * R + by + tx] = tile[tx][ty + i];
}

// ------------------ LayerNorm (1024 cols), bf16 input ----------------------
template <bool OUT_F32>
__global__ void layernorm_bf16(const unsigned short* __restrict__ in, float* outf,
                               unsigned short* outb,
                               const float* __restrict__ g, const float* __restrict__ b) {
    const long row = blockIdx.x;
    const int t = threadIdx.x;
    const ushort4 u = ((const ushort4*)(in + row * 1024))[t];
    float4 v;
    v.x = b2f(u.x); v.y = b2f(u.y); v.z = b2f(u.z); v.w = b2f(u.w);
    float s = v.x + v.y + v.z + v.w;
    float q = v.x * v.x + v.y * v.y + v.z * v.z + v.w * v.w;
#pragma unroll
    for (int off = 32; off > 0; off >>= 1) {
        s += __shfl_down(s, off);
        q += __shfl_down(q, off);
    }
    __shared__ float red[8];
    if ((t & 63) == 0) { red[t >> 6] = s; red[4 + (t >> 6)] = q; }
    __syncthreads();
    s = red[0] + red[1] + red[2] + red[3];
    q = red[4] + red[5] + red[6] + red[7];
    const float mean = s * (1.0f / 1024.0f);
    const float var  = q * (1.0f / 1024.0f) - mean * mean;
    const float inv  = rsqrtf(var + 1e-5f);
    const float4 gg = ((const float4*)g)[t];
    const float4 bb = ((const float4*)b)[t];
    float4 o;
    o.x = (v.x - mean) * inv * gg.x + bb.x;
    o.y = (v.y - mean) * inv * gg.y + bb.y;
    o.z = (v.z - mean) * inv * gg.z + bb.z;
    o.w = (v.w - mean) * inv * gg.w + bb.w;
    if constexpr (OUT_F32) {
        ((float4*)(outf + row * 1024))[t] = o;
    } else {
        ushort4 ob;
        ob.x = f2b(o.x); ob.y = f2b(o.y); ob.z = f2b(o.z); ob.w = f2b(o.w);
        ((ushort4*)(outb + row * 1024))[t] = ob;
    }
}

// ---------------------------------------------------------------------------
extern "C" void kernel_launch(void* const* d_in, const int* in_sizes, int n_in,
                              void* d_out, int out_size, void* d_ws, size_t ws_size,
                              hipStream_t stream) {
    (void)in_sizes; (void)n_in; (void)out_size; (void)ws_size;
    const float* x   = (const float*)d_in[0];
    const float* wq  = (const float*)d_in[1];
    const float* bq  = (const float*)d_in[2];
    const float* wk  = (const float*)d_in[3];
    const float* bk  = (const float*)d_in[4];
    const float* wv  = (const float*)d_in[5];
    const float* bv  = (const float*)d_in[6];
    const float* wo  = (const float*)d_in[7];
    const float* bo  = (const float*)d_in[8];
    const float* w1  = (const float*)d_in[9];
    const float* b1  = (const float*)d_in[10];
    const float* w2  = (const float*)d_in[11];
    const float* b2  = (const float*)d_in[12];
    const float* g1  = (const float*)d_in[13];
    const float* be1 = (const float*)d_in[14];
    const float* g2  = (const float*)d_in[15];
    const float* be2 = (const float*)d_in[16];

    const int D = 1024, FF = 4096, T = 2048, M = 8192;
    const size_t MB = 1ull << 20;
    char* w = (char*)d_ws;
    unsigned short* wqT = (unsigned short*)(w + 0 * MB);    // [3072][1024] wcat
    unsigned short* woT = (unsigned short*)(w + 6 * MB);    // [1024][1024]
    unsigned short* w1T = (unsigned short*)(w + 8 * MB);    // [4096][1024]
    unsigned short* w2T = (unsigned short*)(w + 16 * MB);   // [1024][4096]
    unsigned short* xb  = (unsigned short*)(w + 24 * MB);   // [8192][1024]
    unsigned short* qkv = (unsigned short*)(w + 40 * MB);   // [8192][3072]
    float*          bcat = (float*)(w + 88 * MB);           // [3072]
    unsigned short* vT  = (unsigned short*)(w + 88 * MB);   // [4][1024][2048]
    unsigned short* pr  = (unsigned short*)(w + 104 * MB);  // [4][2048][2048] bf16
    unsigned short* ctxb = (unsigned short*)(w + 136 * MB); // [8192][1024] bf16
    // rsum aliases t0's first 32 KB: rsum lifetime = [transpose_cast4 zero ..
    // ctx read]; t0 born at oproj (strictly after ctx) -> disjoint.
    float*          rsum = (float*)(w + 152 * MB);          // [8192] fp32
    unsigned short* t0  = (unsigned short*)(w + 152 * MB);  // [8192][1024] bf16
    unsigned short* x1b = (unsigned short*)(w + 56 * MB);   // [8192][1024] bf16
    unsigned short* h   = (unsigned short*)(w + 88 * MB);   // [8192][4096] bf16
    unsigned short* y   = (unsigned short*)(w + 168 * MB);  // [8192][1024] bf16

    const dim3 tb(32, 8);
    // weight transposes + casts; transpose_cast4 also zeroes rsum
    transpose_cast4<<<dim3(32, 32, 4), tb, 0, stream>>>(wq, wk, wv, wo, wqT, D, rsum, 2 * M);
    transpose_cast<<<dim3(128, 32), tb, 0, stream>>>(w1, w1T, D, FF);
    transpose_cast<<<dim3(32, 128), tb, 0, stream>>>(w2, w2T, FF, D);
    concat3<<<4, 256, 0, stream>>>(bq, bk, bv, bcat, D);
    cast_f32_bf16<<<8192, 256, 0, stream>>>(x, xb, (long)M * D);

    // Fused QKV projection (8-phase 256^2): [8192][3072] = xb @ wcat^T + bcat
    gemm8<0><<<dim3(12, 32, 1), 512, 0, stream>>>(xb, D, wqT, D, qkv, 3 * D, bcat,
                                                  nullptr, 0,
                                                  M, 3 * D, D, 0, 0, 0, 1.0f);

    // V transpose per batch: view [2048][1024] (stride 3072) -> [1024][2048]
    transpose_bf16<<<dim3(32, 64, 4), tb, 0, stream>>>(qkv + 2 * D, (long)T * 3 * D, 3 * D,
                                                       vT, (long)D * T, T, D);

    // P = exp(q @ k^T / sqrt(128) - 16) bf16 + fused fp32 row-sum atomics
    gemm8<1><<<dim3(8, 8, 4), 512, 0, stream>>>(qkv, 3 * D, qkv + D, 3 * D, pr, T,
                                                nullptr, rsum, T,
                                                T, T, D,
                                                (long)T * 3 * D, (long)T * 3 * D, (long)T * T,
                                                0.08838834764831845f);

    // ctx = (P @ v) / rsum   (128 output 256-tiles -> 128^2 kernel, BK=128)
    gemm_bt<2, 128><<<dim3(8, 16, 4), 256, 0, stream>>>(pr, T, vT, T, ctxb, D,
                                                        nullptr, nullptr, 0, rsum, T, D, T,
                                                        (long)T * T, (long)D * T, (long)T * D, T, 1.0f);

    // o-projection + residual (bf16 xb), bf16 out (128^2 kernel)
    gemm_bt<3, 128><<<dim3(8, 64, 1), 256, 0, stream>>>(ctxb, D, woT, D, t0, D, bo, xb, D,
                                                        nullptr, M, D, D, 0, 0, 0, 0, 1.0f);

    // LN1 (bf16 in) -> bf16 x1b (FFN input + FFN2 residual)
    layernorm_bf16<false><<<8192, 256, 0, stream>>>(t0, nullptr, x1b, g1, be1);

    // FFN1 (128^2 kernel, BK=64 — measured 71.5us vs gemm8's 76.8)
    gemm_bt<4, 64><<<dim3(32, 64, 1), 256, 0, stream>>>(x1b, D, w1T, D, h, FF, b1, nullptr, 0,
                                                        nullptr, M, FF, D, 0, 0, 0, 0, 1.0f);
    // FFN2 (128^2 kernel, K=4096)
    gemm_bt<3, 128><<<dim3(8, 64, 1), 256, 0, stream>>>(h, FF, w2T, FF, y, D, b2, x1b, D,
                                                        nullptr, M, D, FF, 0, 0, 0, 0, 1.0f);

    // LN2 (bf16 in) -> output (fp32)
    layernorm_bf16<true><<<8192, 256, 0, stream>>>(y, (float*)d_out, nullptr, g2, be2);
}

// Round 5
// 447.799 us; speedup vs baseline: 1.1873x; 1.1174x over previous
//
#include <hip/hip_runtime.h>
#include <hip/hip_bf16.h>
#include <stdint.h>

// ---------------------------------------------------------------------------
// SmallTransformerBlock on MI355X (gfx950)  — Round 13
//   B=4, T=2048, D=1024, FF=4096, full-D attention, scale = sqrt(128)
// R12 -> R13 (trust within-run dispatch A/B, not cross-container walls):
//   * ALL GEMMs on gemm_bt (128^2). gemm8 deleted: at K=1024 it loses to
//     gemm_bt at every shape (FFN1 76.8 vs 71.5 measured; QKV ~77 via
//     1.5-round quantization at 1 block/CU vs ~54 on a 1536-block grid).
//   * QKV -> gemm_bt<0,64> grid 24x64 (6 even rounds).
//   * scores -> gemm_bt<1,64> grid 16x16x4 (4 even rounds) with R12's
//     fused fp32 rowsum epilogue (shfl_xor + atomicAdd, rowsum_inv stays
//     deleted).
//   * prep fusion: {wq/wk/wv/wo transpose, w1T, w2T, x-cast, bcat concat,
//     rsum zero} -> ONE job-table kernel. Launches 13 -> 10.
//   * NOTE: MfmaUtil on gfx950 (gfx94x formula) overcounts ~3x; true MFMA
//     issue util here is 11-23% -> kernels are schedule-bound, not roofline.
// ---------------------------------------------------------------------------

typedef __bf16 bf16x8 __attribute__((ext_vector_type(8)));
typedef float f32x4 __attribute__((ext_vector_type(4)));

__device__ __forceinline__ unsigned short f2b(float f) {
    __hip_bfloat16 h = __float2bfloat16(f);
    unsigned short u;
    __builtin_memcpy(&u, &h, 2);
    return u;
}

__device__ __forceinline__ float b2f(unsigned short u) {
    __hip_bfloat16 h;
    __builtin_memcpy(&h, &u, 2);
    return __bfloat162float(h);
}

__device__ __forceinline__ void async_copy16(const unsigned short* g, unsigned short* l) {
    __builtin_amdgcn_global_load_lds((__attribute__((address_space(1))) void*)(g),
                                     (__attribute__((address_space(3))) void*)(l),
                                     16, 0, 0);
}

// ---------------------------------------------------------------------------
// 128^2-tile GEMM — the workhorse for every matmul in the block:
// MODE 0: +bias                  (fused QKV)
// MODE 1: exp(acc*scale-16) + fused fp32 row-sum atomicAdd  (scores)
// MODE 2: /rowsum[z*sR + row]    (ctx = P @ V, normalized)
// MODE 3: +bias, +resid(bf16)    (o-proj, FFN2)
// MODE 4: +bias, relu            (FFN1)
// Tile 128x128, BK in {64,128}, block = 256, grid (N/128, M/128, batch).
// ---------------------------------------------------------------------------
template <int MODE, int BK>
__launch_bounds__(256, 2)
__global__ void gemm_bt(const unsigned short* __restrict__ A, int lda,
                        const unsigned short* __restrict__ Bt, int ldb,
                        unsigned short* __restrict__ Cv, int ldc,
                        const float* __restrict__ bias,
                        const unsigned short* __restrict__ resid, int ldr,
                        float* __restrict__ rowsum,
                        int M, int N, int K,
                        long sA, long sB, long sC, long sR, float scale) {
    constexpr bool HAS_BIAS  = (MODE == 0 || MODE == 3 || MODE == 4);
    constexpr bool HAS_RESID = (MODE == 3);
    constexpr bool RELU      = (MODE == 4);
    constexpr bool EXPW      = (MODE == 1);
    constexpr bool ROWSCALE  = (MODE == 2);
    constexpr int  CPR = BK / 8;    // 16B chunks per row
    constexpr int  P   = BK / 16;   // staging groups of 256 chunks per operand
    constexpr int  KS  = BK / 32;   // 32-k steps per tile

    __shared__ unsigned short lds_us[256 * BK];  // A[128][BK] + B[128][BK]
    unsigned short* ldsA = lds_us;
    unsigned short* ldsB = lds_us + 128 * BK;

    // XCD-aware swizzle (ny % 8 == 0 for all our grids)
    const int nx = (int)gridDim.x, ny = (int)gridDim.y;
    int bx, by;
    if ((ny & 7) == 0) {
        const int n     = (int)blockIdx.y * nx + (int)blockIdx.x;
        const int xcd   = n & 7;
        const int slot  = n >> 3;
        const int bandh = ny >> 3;
        by = xcd * bandh + (slot % bandh);
        bx = slot / bandh;
    } else {
        bx = (int)blockIdx.x;
        by = (int)blockIdx.y;
    }

    const int z = blockIdx.z;
    const unsigned short* Ab = A + (long)z * sA + (long)by * 128 * lda;
    const unsigned short* Bb = Bt + (long)z * sB + (long)bx * 128 * ldb;

    const int tid  = threadIdx.x;
    const int lane = tid & 63;
    const int wid  = tid >> 6;
    const int wr   = wid >> 1;
    const int wc   = wid & 1;

    f32x4 acc[4][4] = {};

    long offA[P], offB[P];
    unsigned short* dA[P];
    unsigned short* dB[P];
#pragma unroll
    for (int p = 0; p < P; ++p) {
        const int s = p * 256 + tid;
        const int r = s / CPR;
        const int c = ((s & (CPR - 1)) ^ (r & (CPR - 1))) * 8;
        offA[p] = (long)r * lda + c;
        offB[p] = (long)r * ldb + c;
        dA[p] = ldsA + (p * 256 + wid * 64) * 8;
        dB[p] = ldsB + (p * 256 + wid * 64) * 8;
    }

    const int kq = lane >> 4;
    const int rr = lane & 15;

    for (int k0 = 0; k0 < K; k0 += BK) {
        __syncthreads();
#pragma unroll
        for (int p = 0; p < P; ++p) {
            async_copy16(Ab + offA[p] + k0, dA[p]);
            async_copy16(Bb + offB[p] + k0, dB[p]);
        }
        __syncthreads();

#pragma unroll
        for (int ks = 0; ks < KS; ++ks) {
            const int st = (ks * 4 + kq) ^ (rr & (CPR - 1));
            bf16x8 af[4], bfr[4];
#pragma unroll
            for (int mi = 0; mi < 4; ++mi)
                af[mi] = *(const bf16x8*)(ldsA + (wr * 64 + mi * 16 + rr) * BK + st * 8);
#pragma unroll
            for (int ni = 0; ni < 4; ++ni)
                bfr[ni] = *(const bf16x8*)(ldsB + (wc * 64 + ni * 16 + rr) * BK + st * 8);
#pragma unroll
            for (int mi = 0; mi < 4; ++mi)
#pragma unroll
                for (int ni = 0; ni < 4; ++ni)
                    acc[mi][ni] = __builtin_amdgcn_mfma_f32_16x16x32_bf16(af[mi], bfr[ni], acc[mi][ni], 0, 0, 0);
        }
    }

    // Epilogue. C/D layout: col = lane&15, row = (lane>>4)*4 + reg
    const long zC = (long)z * sC;
    const int colb = bx * 128 + wc * 64 + rr;
    const int rowb = by * 128 + wr * 64 + kq * 4;
    if constexpr (EXPW) {
        // exp + fused row-sum: per (mi,r) the 16 rr-lanes x 4 n-frags cover
        // 64 cols of one row (kq groups = 4 distinct rows). fp32 partial,
        // shfl_xor reduce over the 16-lane group, 1 atomicAdd per row/wave.
#pragma unroll
        for (int mi = 0; mi < 4; ++mi) {
#pragma unroll
            for (int r = 0; r < 4; ++r) {
                const int row = rowb + mi * 16 + r;
                float part = 0.0f;
#pragma unroll
                for (int ni = 0; ni < 4; ++ni) {
                    const int col = colb + ni * 16;
                    float v = __expf(acc[mi][ni][r] * scale - 16.0f);
                    part += v;
                    Cv[zC + (long)row * ldc + col] = f2b(v);
                }
                part += __shfl_xor(part, 1);
                part += __shfl_xor(part, 2);
                part += __shfl_xor(part, 4);
                part += __shfl_xor(part, 8);
                if (rr == 0) atomicAdd(&rowsum[(long)z * sR + row], part);
            }
        }
    } else {
#pragma unroll
        for (int mi = 0; mi < 4; ++mi) {
            float inv_r[4];
            if constexpr (ROWSCALE) {
#pragma unroll
                for (int r = 0; r < 4; ++r)
                    inv_r[r] = 1.0f / rowsum[(long)z * sR + (rowb + mi * 16 + r)];
            }
#pragma unroll
            for (int ni = 0; ni < 4; ++ni) {
                const int col = colb + ni * 16;
                float bv = 0.0f;
                if constexpr (HAS_BIAS) bv = bias[col];
#pragma unroll
                for (int r = 0; r < 4; ++r) {
                    const int row = rowb + mi * 16 + r;
                    float v = acc[mi][ni][r] * scale + bv;
                    if constexpr (ROWSCALE) v *= inv_r[r];
                    if constexpr (HAS_RESID) v += b2f(resid[(long)z * sR + (long)row * ldr + col]);
                    if constexpr (RELU) v = v > 0.0f ? v : 0.0f;
                    Cv[zC + (long)row * ldc + col] = f2b(v);
                }
            }
        }
    }
}

// ---------------------------------------------------------------------------
// prep: all input preprocessing in ONE launch (job table by blockIdx.x):
//   [0,4096)      wq/wk/wv/wo f32 -> bf16 transposed into wqT (contiguous)
//   [4096,8192)   w1 [1024][4096] -> w1T [4096][1024]
//   [8192,12288)  w2 [4096][1024] -> w2T [1024][4096]
//   [12288,20480) x f32 -> xb bf16 (8192 * 1024 elems, 1024/block)
//   [20480,20492) bcat = concat(bq, bk, bv)
//   [20492,20524) rsum[0:8192) = 0
// block = 256 threads. All jobs independent.
// ---------------------------------------------------------------------------
__global__ void prep(const float* __restrict__ wq, const float* __restrict__ wk,
                     const float* __restrict__ wv, const float* __restrict__ wo,
                     unsigned short* __restrict__ wqT,
                     const float* __restrict__ w1, unsigned short* __restrict__ w1T,
                     const float* __restrict__ w2, unsigned short* __restrict__ w2T,
                     const float* __restrict__ x, unsigned short* __restrict__ xb,
                     const float* __restrict__ bq, const float* __restrict__ bk,
                     const float* __restrict__ bv, float* __restrict__ bcat,
                     float* __restrict__ rsum) {
    const int job = blockIdx.x;
    const int tid = threadIdx.x;
    if (job < 12288) {
        __shared__ float tile[32][33];
        const int tx = tid & 31, ty = tid >> 5;
        const float* src;
        unsigned short* dst;
        int R, C, bx, by;
        if (job < 4096) {
            const int m = job >> 10, t = job & 1023;
            src = (m == 0) ? wq : (m == 1) ? wk : (m == 2) ? wv : wo;
            dst = wqT + (long)m * 1024 * 1024;
            R = 1024; C = 1024;
            bx = (t & 31) * 32; by = (t >> 5) * 32;
        } else if (job < 8192) {
            const int t = job - 4096;
            src = w1; dst = w1T; R = 1024; C = 4096;
            bx = (t & 127) * 32; by = (t >> 7) * 32;
        } else {
            const int t = job - 8192;
            src = w2; dst = w2T; R = 4096; C = 1024;
            bx = (t & 31) * 32; by = (t >> 5) * 32;
        }
#pragma unroll
        for (int i = 0; i < 32; i += 8)
            tile[ty + i][tx] = src[(long)(by + ty + i) * C + bx + tx];
        __syncthreads();
#pragma unroll
        for (int i = 0; i < 32; i += 8)
            dst[(long)(bx + ty + i) * R + by + tx] = f2b(tile[tx][ty + i]);
    } else if (job < 20480) {
        const long i = ((long)(job - 12288) * 256 + tid) * 4;
        const float4 v = *(const float4*)(x + i);
        ushort4 o;
        o.x = f2b(v.x); o.y = f2b(v.y); o.z = f2b(v.z); o.w = f2b(v.w);
        *(ushort4*)(xb + i) = o;
    } else if (job < 20492) {
        const int i = (job - 20480) * 256 + tid;  // 0..3071
        bcat[i] = (i < 1024) ? bq[i] : (i < 2048) ? bk[i - 1024] : bv[i - 2048];
    } else {
        const int i = (job - 20492) * 256 + tid;  // 0..8191
        rsum[i] = 0.0f;
    }
}

// -------- transpose bf16 [R][C] (row stride ld) -> [C][R], batched ---------
__global__ void transpose_bf16(const unsigned short* __restrict__ src, long sS, int ld,
                               unsigned short* __restrict__ dst, long sD, int R, int C) {
    const int z = blockIdx.z;
    src += (long)z * sS;
    dst += (long)z * sD;
    __shared__ unsigned short tile[32][33];
    const int bx = blockIdx.x * 32;
    const int by = blockIdx.y * 32;
    const int tx = threadIdx.x, ty = threadIdx.y;
#pragma unroll
    for (int i = 0; i < 32; i += 8)
        tile[ty + i][tx] = src[(long)(by + ty + i) * ld + bx + tx];
    __syncthreads();
#pragma unroll
    for (int i = 0; i < 32; i += 8)
        dst[(long)(bx + ty + i) * R + by + tx] = tile[tx][ty + i];
}

// ------------------ LayerNorm (1024 cols), bf16 input ----------------------
template <bool OUT_F32>
__global__ void layernorm_bf16(const unsigned short* __restrict__ in, float* outf,
                               unsigned short* outb,
                               const float* __restrict__ g, const float* __restrict__ b) {
    const long row = blockIdx.x;
    const int t = threadIdx.x;
    const ushort4 u = ((const ushort4*)(in + row * 1024))[t];
    float4 v;
    v.x = b2f(u.x); v.y = b2f(u.y); v.z = b2f(u.z); v.w = b2f(u.w);
    float s = v.x + v.y + v.z + v.w;
    float q = v.x * v.x + v.y * v.y + v.z * v.z + v.w * v.w;
#pragma unroll
    for (int off = 32; off > 0; off >>= 1) {
        s += __shfl_down(s, off);
        q += __shfl_down(q, off);
    }
    __shared__ float red[8];
    if ((t & 63) == 0) { red[t >> 6] = s; red[4 + (t >> 6)] = q; }
    __syncthreads();
    s = red[0] + red[1] + red[2] + red[3];
    q = red[4] + red[5] + red[6] + red[7];
    const float mean = s * (1.0f / 1024.0f);
    const float var  = q * (1.0f / 1024.0f) - mean * mean;
    const float inv  = rsqrtf(var + 1e-5f);
    const float4 gg = ((const float4*)g)[t];
    const float4 bb = ((const float4*)b)[t];
    float4 o;
    o.x = (v.x - mean) * inv * gg.x + bb.x;
    o.y = (v.y - mean) * inv * gg.y + bb.y;
    o.z = (v.z - mean) * inv * gg.z + bb.z;
    o.w = (v.w - mean) * inv * gg.w + bb.w;
    if constexpr (OUT_F32) {
        ((float4*)(outf + row * 1024))[t] = o;
    } else {
        ushort4 ob;
        ob.x = f2b(o.x); ob.y = f2b(o.y); ob.z = f2b(o.z); ob.w = f2b(o.w);
        ((ushort4*)(outb + row * 1024))[t] = ob;
    }
}

// ---------------------------------------------------------------------------
extern "C" void kernel_launch(void* const* d_in, const int* in_sizes, int n_in,
                              void* d_out, int out_size, void* d_ws, size_t ws_size,
                              hipStream_t stream) {
    (void)in_sizes; (void)n_in; (void)out_size; (void)ws_size;
    const float* x   = (const float*)d_in[0];
    const float* wq  = (const float*)d_in[1];
    const float* bq  = (const float*)d_in[2];
    const float* wk  = (const float*)d_in[3];
    const float* bk  = (const float*)d_in[4];
    const float* wv  = (const float*)d_in[5];
    const float* bv  = (const float*)d_in[6];
    const float* wo  = (const float*)d_in[7];
    const float* bo  = (const float*)d_in[8];
    const float* w1  = (const float*)d_in[9];
    const float* b1  = (const float*)d_in[10];
    const float* w2  = (const float*)d_in[11];
    const float* b2  = (const float*)d_in[12];
    const float* g1  = (const float*)d_in[13];
    const float* be1 = (const float*)d_in[14];
    const float* g2  = (const float*)d_in[15];
    const float* be2 = (const float*)d_in[16];

    const int D = 1024, FF = 4096, T = 2048, M = 8192;
    const size_t MB = 1ull << 20;
    char* w = (char*)d_ws;
    unsigned short* wqT = (unsigned short*)(w + 0 * MB);    // [3072+1024][1024] wcat+woT
    unsigned short* woT = (unsigned short*)(w + 6 * MB);    // [1024][1024] (= wqT+3*D*D)
    unsigned short* w1T = (unsigned short*)(w + 8 * MB);    // [4096][1024]
    unsigned short* w2T = (unsigned short*)(w + 16 * MB);   // [1024][4096]
    unsigned short* xb  = (unsigned short*)(w + 24 * MB);   // [8192][1024]
    unsigned short* qkv = (unsigned short*)(w + 40 * MB);   // [8192][3072]
    float*          bcat = (float*)(w + 88 * MB);           // [3072], dead before vT
    unsigned short* vT  = (unsigned short*)(w + 88 * MB);   // [4][1024][2048]
    unsigned short* pr  = (unsigned short*)(w + 104 * MB);  // [4][2048][2048] bf16
    unsigned short* ctxb = (unsigned short*)(w + 136 * MB); // [8192][1024] bf16
    // rsum aliases t0's first 32 KB: rsum lifetime = [prep zero .. ctx read];
    // t0 born at oproj (strictly after ctx) -> disjoint.
    float*          rsum = (float*)(w + 152 * MB);          // [8192] fp32
    unsigned short* t0  = (unsigned short*)(w + 152 * MB);  // [8192][1024] bf16
    unsigned short* x1b = (unsigned short*)(w + 56 * MB);   // [8192][1024] bf16
    unsigned short* h   = (unsigned short*)(w + 88 * MB);   // [8192][4096] bf16
    unsigned short* y   = (unsigned short*)(w + 168 * MB);  // [8192][1024] bf16

    // ---- all preprocessing in one launch (weights T+cast, x cast, bcat,
    //      rsum zero). wqT holds wq|wk|wv|wo transposed contiguously.
    prep<<<20524, 256, 0, stream>>>(wq, wk, wv, wo, wqT, w1, w1T, w2, w2T,
                                    x, xb, bq, bk, bv, bcat, rsum);

    // Fused QKV projection: [8192][3072] = xb @ wcat^T + bcat  (24x64 grid,
    // 1536 blocks = 6 even rounds; gemm8's 384-block grid wasted 0.5 round)
    gemm_bt<0, 64><<<dim3(24, 64, 1), 256, 0, stream>>>(xb, D, wqT, D, qkv, 3 * D, bcat,
                                                        nullptr, 0, nullptr,
                                                        M, 3 * D, D, 0, 0, 0, 0, 1.0f);

    // V transpose per batch: view [2048][1024] (stride 3072) -> [1024][2048]
    transpose_bf16<<<dim3(32, 64, 4), dim3(32, 8), 0, stream>>>(
        qkv + 2 * D, (long)T * 3 * D, 3 * D, vT, (long)D * T, T, D);

    // P = exp(q @ k^T / sqrt(128) - 16) bf16 + fused fp32 row-sum atomics
    gemm_bt<1, 64><<<dim3(16, 16, 4), 256, 0, stream>>>(qkv, 3 * D, qkv + D, 3 * D, pr, T,
                                                        nullptr, nullptr, 0, rsum,
                                                        T, T, D,
                                                        (long)T * 3 * D, (long)T * 3 * D,
                                                        (long)T * T, T,
                                                        0.08838834764831845f);

    // ctx = (P @ v) / rsum   (512 blocks -> BK=128)
    gemm_bt<2, 128><<<dim3(8, 16, 4), 256, 0, stream>>>(pr, T, vT, T, ctxb, D,
                                                        nullptr, nullptr, 0, rsum, T, D, T,
                                                        (long)T * T, (long)D * T, (long)T * D, T, 1.0f);

    // o-projection + residual (bf16 xb), bf16 out (512 blocks -> BK=128)
    gemm_bt<3, 128><<<dim3(8, 64, 1), 256, 0, stream>>>(ctxb, D, woT, D, t0, D, bo, xb, D,
                                                        nullptr, M, D, D, 0, 0, 0, 0, 1.0f);

    // LN1 (bf16 in) -> bf16 x1b (FFN input + FFN2 residual)
    layernorm_bf16<false><<<8192, 256, 0, stream>>>(t0, nullptr, x1b, g1, be1);

    // FFN1 (2048 blocks -> BK=64)
    gemm_bt<4, 64><<<dim3(32, 64, 1), 256, 0, stream>>>(x1b, D, w1T, D, h, FF, b1, nullptr, 0,
                                                        nullptr, M, FF, D, 0, 0, 0, 0, 1.0f);
    // FFN2 (512 blocks -> BK=128)
    gemm_bt<3, 128><<<dim3(8, 64, 1), 256, 0, stream>>>(h, FF, w2T, FF, y, D, b2, x1b, D,
                                                        nullptr, M, D, FF, 0, 0, 0, 0, 1.0f);

    // LN2 (bf16 in) -> output (fp32)
    layernorm_bf16<true><<<8192, 256, 0, stream>>>(y, (float*)d_out, nullptr, g2, be2);
}

// Round 6
// 441.268 us; speedup vs baseline: 1.2049x; 1.0148x over previous
//
#include <hip/hip_runtime.h>
#include <hip/hip_bf16.h>
#include <stdint.h>

// ---------------------------------------------------------------------------
// SmallTransformerBlock on MI355X (gfx950)  — Round 14
//   B=4, T=2048, D=1024, FF=4096, full-D attention, scale = sqrt(128)
// R13 -> R14 (consolidation; keep the 447.8us-measured base):
//   * gemm_bt body extracted into gemm_tile<MODE,BK> device fn (identical
//     codegen path).
//   * NEW attn_mid kernel: blocks 0..1023 = scores GEMM tiles (MODE 1,
//     same XCD-swizzle mapping, verified bijective), blocks 1024..9215 =
//     V-transpose 32x32 tiles. Both depend only on QKV -> one launch
//     replaces {transpose_bf16, scores}; transpose packs behind scores.
//     Launches 10 -> 9.
//   * Everything else unchanged from R13 (measured best per dispatch).
//   * Note: GEMMs sit at the m97-structure ceiling (~900-960 TF); both
//     8-phase attempts regressed on these K=1024 shapes -> not retrying.
// ---------------------------------------------------------------------------

typedef __bf16 bf16x8 __attribute__((ext_vector_type(8)));
typedef float f32x4 __attribute__((ext_vector_type(4)));

__device__ __forceinline__ unsigned short f2b(float f) {
    __hip_bfloat16 h = __float2bfloat16(f);
    unsigned short u;
    __builtin_memcpy(&u, &h, 2);
    return u;
}

__device__ __forceinline__ float b2f(unsigned short u) {
    __hip_bfloat16 h;
    __builtin_memcpy(&h, &u, 2);
    return __bfloat162float(h);
}

__device__ __forceinline__ void async_copy16(const unsigned short* g, unsigned short* l) {
    __builtin_amdgcn_global_load_lds((__attribute__((address_space(1))) void*)(g),
                                     (__attribute__((address_space(3))) void*)(l),
                                     16, 0, 0);
}

// ---------------------------------------------------------------------------
// gemm_tile: one 128x128 output tile of C = A @ Bt^T  (A,Bt bf16, K-contig).
// MODE 0: +bias                  (fused QKV)
// MODE 1: exp(acc*scale-16) + fused fp32 row-sum atomicAdd  (scores)
// MODE 2: /rowsum[z*sR + row]    (ctx = P @ V, normalized)
// MODE 3: +bias, +resid(bf16)    (o-proj, FFN2)
// MODE 4: +bias, relu            (FFN1)
// ---------------------------------------------------------------------------
template <int MODE, int BK>
__device__ __forceinline__ void gemm_tile(
    unsigned short* lds_us,
    const unsigned short* __restrict__ A, int lda,
    const unsigned short* __restrict__ Bt, int ldb,
    unsigned short* __restrict__ Cv, int ldc,
    const float* __restrict__ bias,
    const unsigned short* __restrict__ resid, int ldr,
    float* __restrict__ rowsum,
    int K, long sA, long sB, long sC, long sR, float scale,
    int bx, int by, int z)
{
    constexpr bool HAS_BIAS  = (MODE == 0 || MODE == 3 || MODE == 4);
    constexpr bool HAS_RESID = (MODE == 3);
    constexpr bool RELU      = (MODE == 4);
    constexpr bool EXPW      = (MODE == 1);
    constexpr bool ROWSCALE  = (MODE == 2);
    constexpr int  CPR = BK / 8;    // 16B chunks per row
    constexpr int  P   = BK / 16;   // staging groups of 256 chunks per operand
    constexpr int  KS  = BK / 32;   // 32-k steps per tile

    unsigned short* ldsA = lds_us;
    unsigned short* ldsB = lds_us + 128 * BK;

    const unsigned short* Ab = A + (long)z * sA + (long)by * 128 * lda;
    const unsigned short* Bb = Bt + (long)z * sB + (long)bx * 128 * ldb;

    const int tid  = threadIdx.x;
    const int lane = tid & 63;
    const int wid  = tid >> 6;
    const int wr   = wid >> 1;
    const int wc   = wid & 1;

    f32x4 acc[4][4] = {};

    long offA[P], offB[P];
    unsigned short* dA[P];
    unsigned short* dB[P];
#pragma unroll
    for (int p = 0; p < P; ++p) {
        const int s = p * 256 + tid;
        const int r = s / CPR;
        const int c = ((s & (CPR - 1)) ^ (r & (CPR - 1))) * 8;
        offA[p] = (long)r * lda + c;
        offB[p] = (long)r * ldb + c;
        dA[p] = ldsA + (p * 256 + wid * 64) * 8;
        dB[p] = ldsB + (p * 256 + wid * 64) * 8;
    }

    const int kq = lane >> 4;
    const int rr = lane & 15;

    for (int k0 = 0; k0 < K; k0 += BK) {
        __syncthreads();
#pragma unroll
        for (int p = 0; p < P; ++p) {
            async_copy16(Ab + offA[p] + k0, dA[p]);
            async_copy16(Bb + offB[p] + k0, dB[p]);
        }
        __syncthreads();

#pragma unroll
        for (int ks = 0; ks < KS; ++ks) {
            const int st = (ks * 4 + kq) ^ (rr & (CPR - 1));
            bf16x8 af[4], bfr[4];
#pragma unroll
            for (int mi = 0; mi < 4; ++mi)
                af[mi] = *(const bf16x8*)(ldsA + (wr * 64 + mi * 16 + rr) * BK + st * 8);
#pragma unroll
            for (int ni = 0; ni < 4; ++ni)
                bfr[ni] = *(const bf16x8*)(ldsB + (wc * 64 + ni * 16 + rr) * BK + st * 8);
#pragma unroll
            for (int mi = 0; mi < 4; ++mi)
#pragma unroll
                for (int ni = 0; ni < 4; ++ni)
                    acc[mi][ni] = __builtin_amdgcn_mfma_f32_16x16x32_bf16(af[mi], bfr[ni], acc[mi][ni], 0, 0, 0);
        }
    }

    // Epilogue. C/D layout: col = lane&15, row = (lane>>4)*4 + reg
    const long zC = (long)z * sC;
    const int colb = bx * 128 + wc * 64 + rr;
    const int rowb = by * 128 + wr * 64 + kq * 4;
    if constexpr (EXPW) {
        // exp + fused row-sum: per (mi,r) the 16 rr-lanes x 4 n-frags cover
        // 64 cols of one row. fp32 partial, shfl_xor reduce over the 16-lane
        // group, 1 atomicAdd per row per wave.
#pragma unroll
        for (int mi = 0; mi < 4; ++mi) {
#pragma unroll
            for (int r = 0; r < 4; ++r) {
                const int row = rowb + mi * 16 + r;
                float part = 0.0f;
#pragma unroll
                for (int ni = 0; ni < 4; ++ni) {
                    const int col = colb + ni * 16;
                    float v = __expf(acc[mi][ni][r] * scale - 16.0f);
                    part += v;
                    Cv[zC + (long)row * ldc + col] = f2b(v);
                }
                part += __shfl_xor(part, 1);
                part += __shfl_xor(part, 2);
                part += __shfl_xor(part, 4);
                part += __shfl_xor(part, 8);
                if (rr == 0) atomicAdd(&rowsum[(long)z * sR + row], part);
            }
        }
    } else {
#pragma unroll
        for (int mi = 0; mi < 4; ++mi) {
            float inv_r[4];
            if constexpr (ROWSCALE) {
#pragma unroll
                for (int r = 0; r < 4; ++r)
                    inv_r[r] = 1.0f / rowsum[(long)z * sR + (rowb + mi * 16 + r)];
            }
#pragma unroll
            for (int ni = 0; ni < 4; ++ni) {
                const int col = colb + ni * 16;
                float bv = 0.0f;
                if constexpr (HAS_BIAS) bv = bias[col];
#pragma unroll
                for (int r = 0; r < 4; ++r) {
                    const int row = rowb + mi * 16 + r;
                    float v = acc[mi][ni][r] * scale + bv;
                    if constexpr (ROWSCALE) v *= inv_r[r];
                    if constexpr (HAS_RESID) v += b2f(resid[(long)z * sR + (long)row * ldr + col]);
                    if constexpr (RELU) v = v > 0.0f ? v : 0.0f;
                    Cv[zC + (long)row * ldc + col] = f2b(v);
                }
            }
        }
    }
}

// ---------------------------------------------------------------------------
// gemm_bt: standalone launch wrapper. grid (N/128, M/128, batch), block 256.
// ---------------------------------------------------------------------------
template <int MODE, int BK>
__launch_bounds__(256, 2)
__global__ void gemm_bt(const unsigned short* __restrict__ A, int lda,
                        const unsigned short* __restrict__ Bt, int ldb,
                        unsigned short* __restrict__ Cv, int ldc,
                        const float* __restrict__ bias,
                        const unsigned short* __restrict__ resid, int ldr,
                        float* __restrict__ rowsum,
                        int K, long sA, long sB, long sC, long sR, float scale) {
    __shared__ unsigned short lds_us[256 * BK];  // A[128][BK] + B[128][BK]

    // XCD-aware swizzle (ny % 8 == 0 for all our grids)
    const int nx = (int)gridDim.x, ny = (int)gridDim.y;
    int bx, by;
    if ((ny & 7) == 0) {
        const int n     = (int)blockIdx.y * nx + (int)blockIdx.x;
        const int xcd   = n & 7;
        const int slot  = n >> 3;
        const int bandh = ny >> 3;
        by = xcd * bandh + (slot % bandh);
        bx = slot / bandh;
    } else {
        bx = (int)blockIdx.x;
        by = (int)blockIdx.y;
    }

    gemm_tile<MODE, BK>(lds_us, A, lda, Bt, ldb, Cv, ldc, bias, resid, ldr,
                        rowsum, K, sA, sB, sC, sR, scale, bx, by, (int)blockIdx.z);
}

// ---------------------------------------------------------------------------
// attn_mid: one launch for everything that depends only on QKV:
//   blocks [0,1024)     scores tiles: P = exp(q@k^T*scale-16) + rowsum
//                       (z = j>>8; n = j&255; same XCD swizzle, nx=ny=16)
//   blocks [1024,9216)  V-transpose 32x32 tiles: qkv V-part -> vT
// block = 256 threads, LDS 32 KiB (scores) / 2.1 KiB view (transpose).
// ---------------------------------------------------------------------------
__launch_bounds__(256, 2)
__global__ void attn_mid(const unsigned short* __restrict__ qkv,
                         unsigned short* __restrict__ pr,
                         unsigned short* __restrict__ vT,
                         float* __restrict__ rowsum) {
    __shared__ unsigned short lds_us[256 * 64];
    const int j = blockIdx.x;
    if (j < 1024) {
        const int z    = j >> 8;
        const int n    = j & 255;
        const int xcd  = n & 7;          // nx=16, ny=16 -> bandh = 2
        const int slot = n >> 3;
        const int by   = xcd * 2 + (slot & 1);
        const int bx   = slot >> 1;
        gemm_tile<1, 64>(lds_us, qkv, 3072, qkv + 1024, 3072, pr, 2048,
                         nullptr, nullptr, 0, rowsum,
                         1024, (long)2048 * 3072, (long)2048 * 3072,
                         (long)2048 * 2048, 2048,
                         0.08838834764831845f, bx, by, z);
    } else {
        const int t   = j - 1024;
        const int z   = t >> 11;
        const int rem = t & 2047;
        const int bx  = (rem & 31) * 32;   // col base in src (D dim)
        const int by  = (rem >> 5) * 32;   // row base in src (T dim)
        const unsigned short* src = qkv + 2048 + (long)z * 2048 * 3072;
        unsigned short* dst = vT + (long)z * 1024 * 2048;
        unsigned short (*tile)[33] = (unsigned short(*)[33])lds_us;
        const int tx = threadIdx.x & 31, ty = threadIdx.x >> 5;
#pragma unroll
        for (int i = 0; i < 32; i += 8)
            tile[ty + i][tx] = src[(long)(by + ty + i) * 3072 + bx + tx];
        __syncthreads();
#pragma unroll
        for (int i = 0; i < 32; i += 8)
            dst[(long)(bx + ty + i) * 2048 + by + tx] = tile[tx][ty + i];
    }
}

// ---------------------------------------------------------------------------
// prep: all input preprocessing in ONE launch (job table by blockIdx.x):
//   [0,4096)      wq/wk/wv/wo f32 -> bf16 transposed into wqT (contiguous)
//   [4096,8192)   w1 [1024][4096] -> w1T [4096][1024]
//   [8192,12288)  w2 [4096][1024] -> w2T [1024][4096]
//   [12288,20480) x f32 -> xb bf16
//   [20480,20492) bcat = concat(bq, bk, bv)
//   [20492,20524) rsum[0:8192) = 0
// ---------------------------------------------------------------------------
__global__ void prep(const float* __restrict__ wq, const float* __restrict__ wk,
                     const float* __restrict__ wv, const float* __restrict__ wo,
                     unsigned short* __restrict__ wqT,
                     const float* __restrict__ w1, unsigned short* __restrict__ w1T,
                     const float* __restrict__ w2, unsigned short* __restrict__ w2T,
                     const float* __restrict__ x, unsigned short* __restrict__ xb,
                     const float* __restrict__ bq, const float* __restrict__ bk,
                     const float* __restrict__ bv, float* __restrict__ bcat,
                     float* __restrict__ rsum) {
    const int job = blockIdx.x;
    const int tid = threadIdx.x;
    if (job < 12288) {
        __shared__ float tile[32][33];
        const int tx = tid & 31, ty = tid >> 5;
        const float* src;
        unsigned short* dst;
        int R, C, bx, by;
        if (job < 4096) {
            const int m = job >> 10, t = job & 1023;
            src = (m == 0) ? wq : (m == 1) ? wk : (m == 2) ? wv : wo;
            dst = wqT + (long)m * 1024 * 1024;
            R = 1024; C = 1024;
            bx = (t & 31) * 32; by = (t >> 5) * 32;
        } else if (job < 8192) {
            const int t = job - 4096;
            src = w1; dst = w1T; R = 1024; C = 4096;
            bx = (t & 127) * 32; by = (t >> 7) * 32;
        } else {
            const int t = job - 8192;
            src = w2; dst = w2T; R = 4096; C = 1024;
            bx = (t & 31) * 32; by = (t >> 5) * 32;
        }
#pragma unroll
        for (int i = 0; i < 32; i += 8)
            tile[ty + i][tx] = src[(long)(by + ty + i) * C + bx + tx];
        __syncthreads();
#pragma unroll
        for (int i = 0; i < 32; i += 8)
            dst[(long)(bx + ty + i) * R + by + tx] = f2b(tile[tx][ty + i]);
    } else if (job < 20480) {
        const long i = ((long)(job - 12288) * 256 + tid) * 4;
        const float4 v = *(const float4*)(x + i);
        ushort4 o;
        o.x = f2b(v.x); o.y = f2b(v.y); o.z = f2b(v.z); o.w = f2b(v.w);
        *(ushort4*)(xb + i) = o;
    } else if (job < 20492) {
        const int i = (job - 20480) * 256 + tid;  // 0..3071
        bcat[i] = (i < 1024) ? bq[i] : (i < 2048) ? bk[i - 1024] : bv[i - 2048];
    } else {
        const int i = (job - 20492) * 256 + tid;  // 0..8191
        rsum[i] = 0.0f;
    }
}

// ------------------ LayerNorm (1024 cols), bf16 input ----------------------
template <bool OUT_F32>
__global__ void layernorm_bf16(const unsigned short* __restrict__ in, float* outf,
                               unsigned short* outb,
                               const float* __restrict__ g, const float* __restrict__ b) {
    const long row = blockIdx.x;
    const int t = threadIdx.x;
    const ushort4 u = ((const ushort4*)(in + row * 1024))[t];
    float4 v;
    v.x = b2f(u.x); v.y = b2f(u.y); v.z = b2f(u.z); v.w = b2f(u.w);
    float s = v.x + v.y + v.z + v.w;
    float q = v.x * v.x + v.y * v.y + v.z * v.z + v.w * v.w;
#pragma unroll
    for (int off = 32; off > 0; off >>= 1) {
        s += __shfl_down(s, off);
        q += __shfl_down(q, off);
    }
    __shared__ float red[8];
    if ((t & 63) == 0) { red[t >> 6] = s; red[4 + (t >> 6)] = q; }
    __syncthreads();
    s = red[0] + red[1] + red[2] + red[3];
    q = red[4] + red[5] + red[6] + red[7];
    const float mean = s * (1.0f / 1024.0f);
    const float var  = q * (1.0f / 1024.0f) - mean * mean;
    const float inv  = rsqrtf(var + 1e-5f);
    const float4 gg = ((const float4*)g)[t];
    const float4 bb = ((const float4*)b)[t];
    float4 o;
    o.x = (v.x - mean) * inv * gg.x + bb.x;
    o.y = (v.y - mean) * inv * gg.y + bb.y;
    o.z = (v.z - mean) * inv * gg.z + bb.z;
    o.w = (v.w - mean) * inv * gg.w + bb.w;
    if constexpr (OUT_F32) {
        ((float4*)(outf + row * 1024))[t] = o;
    } else {
        ushort4 ob;
        ob.x = f2b(o.x); ob.y = f2b(o.y); ob.z = f2b(o.z); ob.w = f2b(o.w);
        ((ushort4*)(outb + row * 1024))[t] = ob;
    }
}

// ---------------------------------------------------------------------------
extern "C" void kernel_launch(void* const* d_in, const int* in_sizes, int n_in,
                              void* d_out, int out_size, void* d_ws, size_t ws_size,
                              hipStream_t stream) {
    (void)in_sizes; (void)n_in; (void)out_size; (void)ws_size;
    const float* x   = (const float*)d_in[0];
    const float* wq  = (const float*)d_in[1];
    const float* bq  = (const float*)d_in[2];
    const float* wk  = (const float*)d_in[3];
    const float* bk  = (const float*)d_in[4];
    const float* wv  = (const float*)d_in[5];
    const float* bv  = (const float*)d_in[6];
    const float* wo  = (const float*)d_in[7];
    const float* bo  = (const float*)d_in[8];
    const float* w1  = (const float*)d_in[9];
    const float* b1  = (const float*)d_in[10];
    const float* w2  = (const float*)d_in[11];
    const float* b2  = (const float*)d_in[12];
    const float* g1  = (const float*)d_in[13];
    const float* be1 = (const float*)d_in[14];
    const float* g2  = (const float*)d_in[15];
    const float* be2 = (const float*)d_in[16];

    const int D = 1024, FF = 4096, T = 2048, M = 8192;
    const size_t MB = 1ull << 20;
    char* w = (char*)d_ws;
    unsigned short* wqT = (unsigned short*)(w + 0 * MB);    // [3072+1024][1024] wcat+woT
    unsigned short* woT = (unsigned short*)(w + 6 * MB);    // [1024][1024] (= wqT+3*D*D)
    unsigned short* w1T = (unsigned short*)(w + 8 * MB);    // [4096][1024]
    unsigned short* w2T = (unsigned short*)(w + 16 * MB);   // [1024][4096]
    unsigned short* xb  = (unsigned short*)(w + 24 * MB);   // [8192][1024]
    unsigned short* qkv = (unsigned short*)(w + 40 * MB);   // [8192][3072]
    float*          bcat = (float*)(w + 88 * MB);           // [3072], dead before vT
    unsigned short* vT  = (unsigned short*)(w + 88 * MB);   // [4][1024][2048]
    unsigned short* pr  = (unsigned short*)(w + 104 * MB);  // [4][2048][2048] bf16
    unsigned short* ctxb = (unsigned short*)(w + 136 * MB); // [8192][1024] bf16
    // rsum aliases t0's first 32 KB: rsum lifetime = [prep zero .. ctx read];
    // t0 born at oproj (strictly after ctx) -> disjoint.
    float*          rsum = (float*)(w + 152 * MB);          // [8192] fp32
    unsigned short* t0  = (unsigned short*)(w + 152 * MB);  // [8192][1024] bf16
    unsigned short* x1b = (unsigned short*)(w + 56 * MB);   // [8192][1024] bf16
    unsigned short* h   = (unsigned short*)(w + 88 * MB);   // [8192][4096] bf16
    unsigned short* y   = (unsigned short*)(w + 168 * MB);  // [8192][1024] bf16

    // ---- all preprocessing in one launch
    prep<<<20524, 256, 0, stream>>>(wq, wk, wv, wo, wqT, w1, w1T, w2, w2T,
                                    x, xb, bq, bk, bv, bcat, rsum);

    // Fused QKV projection: [8192][3072] = xb @ wcat^T + bcat (24x64 grid)
    gemm_bt<0, 64><<<dim3(24, 64, 1), 256, 0, stream>>>(xb, D, wqT, D, qkv, 3 * D, bcat,
                                                        nullptr, 0, nullptr,
                                                        D, 0, 0, 0, 0, 1.0f);

    // scores (exp + fused rowsum) AND V-transpose in one launch
    attn_mid<<<9216, 256, 0, stream>>>(qkv, pr, vT, rsum);

    // ctx = (P @ v) / rsum   (512 blocks -> BK=128)
    gemm_bt<2, 128><<<dim3(8, 16, 4), 256, 0, stream>>>(pr, T, vT, T, ctxb, D,
                                                        nullptr, nullptr, 0, rsum,
                                                        T,
                                                        (long)T * T, (long)D * T, (long)T * D, T, 1.0f);

    // o-projection + residual (bf16 xb), bf16 out (512 blocks -> BK=128)
    gemm_bt<3, 128><<<dim3(8, 64, 1), 256, 0, stream>>>(ctxb, D, woT, D, t0, D, bo, xb, D,
                                                        nullptr, D, 0, 0, 0, 0, 1.0f);

    // LN1 (bf16 in) -> bf16 x1b (FFN input + FFN2 residual)
    layernorm_bf16<false><<<8192, 256, 0, stream>>>(t0, nullptr, x1b, g1, be1);

    // FFN1 (2048 blocks -> BK=64)
    gemm_bt<4, 64><<<dim3(32, 64, 1), 256, 0, stream>>>(x1b, D, w1T, D, h, FF, b1, nullptr, 0,
                                                        nullptr, D, 0, 0, 0, 0, 1.0f);
    // FFN2 (512 blocks -> BK=128)
    gemm_bt<3, 128><<<dim3(8, 64, 1), 256, 0, stream>>>(h, FF, w2T, FF, y, D, b2, x1b, D,
                                                        nullptr, FF, 0, 0, 0, 0, 1.0f);

    // LN2 (bf16 in) -> output (fp32)
    layernorm_bf16<true><<<8192, 256, 0, stream>>>(y, (float*)d_out, nullptr, g2, be2);
}